// Round 16
// baseline (357.516 us; speedup 1.0000x reference)
//
#include <hip/hip_runtime.h>
#include <hip/hip_bf16.h>

#define BB 2
#define NN 8192
#define CC 128
#define CIN_ 64
#define KK 16
#define EPSV 1e-5f

typedef __attribute__((ext_vector_type(8))) short short8;
typedef __attribute__((ext_vector_type(4))) float f32x4;

// ---------------- workspace layout (float-element offsets) ----------------
// idx (int, B*N*K) occupies [0, 262144)
static const size_t OFF_NF   = 262144;                 // fp32 B*C*N
static const size_t OFF_OUT2 = OFF_NF  + 2097152;      // fp32 B*C*N
static const size_t OFF_Y    = OFF_OUT2 + 2097152;     // bf16 [B*N*K][C]
static const size_t OFF_AQB  = OFF_Y   + 16777216;     // bf16 [B*N][C]
static const size_t OFF_AKB  = OFF_AQB + 1048576;
static const size_t OFF_VFB  = OFF_AKB + 1048576;
static const size_t OFF_WQ2  = OFF_VFB + 1048576;      // bf16 WQ2b [0,8192) + bf16 WVb [8192,16384)
static const size_t OFF_WK2  = OFF_WQ2 + 16384;        // bf16 WK2b
static const size_t OFF_PWT  = OFF_WK2 + 16384;        // fp32 post_w^T [cp][c]
static const size_t OFF_W2B  = OFF_PWT + 16384;        // bf16 (att1@pos2) [c][cp]
static const size_t OFF_A2B  = OFF_W2B + 8192;         // bf16 att2_w [c][cp]
static const size_t OFF_BY   = OFF_A2B + 8192;         // 128
static const size_t OFF_RST  = OFF_BY  + 128;          // B*16 (9 used)  [zeroed]
static const size_t OFF_REDA = OFF_RST + 32;           // 32 reduced GN sums (y)
static const size_t OFF_REDP = OFF_REDA + 32;          // 32 reduced GN sums (post)
static const size_t OFF_S1   = OFF_REDP + 32;
static const size_t OFF_T1   = OFF_S1 + 256;
static const size_t OFF_S2   = OFF_T1 + 256;           // (unused)
static const size_t OFF_T2   = OFF_S2 + 256;
static const size_t OFF_S3   = OFF_T2 + 256;
static const size_t OFF_T3   = OFF_S3 + 256;
static const size_t OFF_PTS4 = OFF_T3 + 256;           // float4 B*N -> 65536 floats
static const size_t OFF_PTA  = OFF_PTS4 + 65536;       // GN partials y: [16][4096]
static const size_t OFF_PTP  = OFF_PTA + 65536;        // GN partials post: [16][4096]

// ---------------- helpers ----------------
__device__ __forceinline__ unsigned fkey_u(float d) {
  unsigned u = __float_as_uint(d);
  return (u & 0x80000000u) ? ~u : (u | 0x80000000u);
}
__device__ __forceinline__ unsigned long long shflx64(unsigned long long v, int m) {
  int lo = __shfl_xor((int)(unsigned)(v & 0xffffffffu), m, 64);
  int hi = __shfl_xor((int)(unsigned)(v >> 32), m, 64);
  return ((unsigned long long)(unsigned)hi << 32) | (unsigned)lo;
}
__device__ __forceinline__ float bf2f(unsigned short u) {
  return __uint_as_float((unsigned)u << 16);
}
__device__ __forceinline__ unsigned short f2bf(float f) {
  __hip_bfloat16 h = __float2bfloat16(f);
  unsigned short r;
  __builtin_memcpy(&r, &h, 2);
  return r;
}
__device__ __forceinline__ unsigned pack2bf(float a, float b) {
  return (unsigned)f2bf(a) | ((unsigned)f2bf(b) << 16);
}

// ---------------- T2: weight prep + pts4 (fused) ----------------
__global__ __launch_bounds__(128) void prep_weights(
    const float* __restrict__ att1_w, const float* __restrict__ wq_w, const float* __restrict__ wk_w,
    const float* __restrict__ pos2_w, const float* __restrict__ att2_w, const float* __restrict__ post_w,
    const float* __restrict__ wv_w,
    const float* __restrict__ wq_b, const float* __restrict__ wk_b, const float* __restrict__ pos2_b,
    const float* __restrict__ att1_b, const float* __restrict__ xyz,
    __hip_bfloat16* __restrict__ WQ2b, __hip_bfloat16* __restrict__ WK2b,
    __hip_bfloat16* __restrict__ WVb, __hip_bfloat16* __restrict__ W2b,
    __hip_bfloat16* __restrict__ A2b, float* __restrict__ PWT, float* __restrict__ bias_y,
    float4* __restrict__ pts4) {
  int blk = blockIdx.x, t = threadIdx.x;
  if (blk < 128) {
    int c = blk;
    __shared__ float row[128];
    row[t] = att1_w[c * 128 + t];
    __syncthreads();
    float sq = 0.f, sk = 0.f, sp = 0.f;
    for (int m = 0; m < 128; ++m) {
      float r = row[m];
      sq = fmaf(r, wq_w[m * 128 + t], sq);
      sk = fmaf(r, wk_w[m * 128 + t], sk);
      sp = fmaf(r, pos2_w[m * 128 + t], sp);
    }
    WQ2b[c * 128 + t] = __float2bfloat16(sq);
    WK2b[c * 128 + t] = __float2bfloat16(sk);
    W2b[c * 128 + t] = __float2bfloat16(sp);   // row-major [c][cp]
  } else if (blk == 128) {
    for (int e = t; e < 16384; e += 128) {
      int c = e >> 7, cp = e & 127;
      A2b[e] = __float2bfloat16(att2_w[e]);    // [c][cp] row-major
      PWT[cp * 128 + c] = post_w[e];           // fp32 transposed
      WVb[e] = __float2bfloat16(wv_w[e]);      // [c][k] row-major
    }
  } else if (blk == 129) {
    float s = att1_b[t];
    for (int m = 0; m < 128; ++m)
      s = fmaf(att1_w[t * 128 + m], wq_b[m] - wk_b[m] + pos2_b[m], s);
    bias_y[t] = s;
  } else {
    int e = (blk - 130) * 128 + t;             // 0..16383
    int b = e >> 13, n = e & 8191;
    const float* X = xyz + b * 3 * NN;
    float x = X[n], y = X[NN + n], z = X[2 * NN + n];
    pts4[e] = make_float4(-2.0f * x, -2.0f * y, -2.0f * z, fmaf(z, z, fmaf(y, y, x * x)));
  }
}

// ---------------- K1: kNN — 8 q/block, 2048 blocks (R16: grid-capped occupancy fix) ----------------
// R15's knn at 1024 blocks = 4 blocks/CU = 4 waves/SIMD was GRID-capped (occupancy
// 37%, VALUBusy 54%, LDS/VGPR allow 10 blocks/CU). 8 queries/block doubles the
// block count -> 8 INDEPENDENT blocks/CU (unlike R20's 8-waves-one-block, these
// don't share barriers). Same total pair-math; candidate loads double (L2, ~8 µs).
// Per-query arithmetic (chunk partition, 8-lane fmin tree, tau sequence, key pack,
// exact top-16) is untouched -> identical selected indices.
#define SLOTS 96
__global__ __launch_bounds__(256) void knn_kernel(const float4* __restrict__ pts4,
                                                  int* __restrict__ idxb,
                                                  float* __restrict__ rst) {
  __shared__ unsigned long long list[8][SLOTS];    // 6 KB
  __shared__ float chm[8][33];
  __shared__ float taus[8];
  __shared__ int cnt[8];
  __shared__ int win[8][16];                       // selected neighbor indices
  __shared__ float redst[2][9];
  int t = threadIdx.x;
  int wid = t >> 6, lane = t & 63;
  int blk = blockIdx.x;              // 0..2047
  int b = blk >> 10;                 // 1024 blocks per batch
  int q0 = (blk & 1023) << 3;        // 8 queries per block
  const float4* P = pts4 + b * NN;
  if (t < 8) cnt[t] = 0;
  float qx[8], qy[8], qz[8];
#pragma unroll
  for (int j = 0; j < 8; ++j) {
    float4 qv = P[q0 + j];
    qx[j] = -0.5f * qv.x; qy[j] = -0.5f * qv.y; qz[j] = -0.5f * qv.z;
  }

  // ---- phase A: 8 lanes/chunk, 8 chunks in parallel; wave wid owns chunks [8w,8w+8) ----
  {
    int g = lane >> 3, s = lane & 7;
    const float4* Pc = P + (wid << 11) + (g << 8);
    float mn[8];
#pragma unroll
    for (int j = 0; j < 8; ++j) mn[j] = 3.4e38f;
    for (int i = 0; i < 32; i += 2) {
      float4 c0 = Pc[(i << 3) + s];
      float4 c1 = Pc[((i + 1) << 3) + s];
#pragma unroll
      for (int j = 0; j < 8; ++j) {
        float d0 = fmaf(qx[j], c0.x, fmaf(qy[j], c0.y, fmaf(qz[j], c0.z, c0.w)));
        float d1 = fmaf(qx[j], c1.x, fmaf(qy[j], c1.y, fmaf(qz[j], c1.z, c1.w)));
        mn[j] = fminf(mn[j], fminf(d0, d1));
      }
    }
#pragma unroll
    for (int off = 1; off < 8; off <<= 1)
#pragma unroll
      for (int j = 0; j < 8; ++j) mn[j] = fminf(mn[j], __shfl_xor(mn[j], off));
    if (s == 0) {
#pragma unroll
      for (int j = 0; j < 8; ++j) chm[j][(wid << 3) + g] = mn[j];
    }
  }
  __syncthreads();

  // ---- tau: thread t<8 handles query t (identical binary-search sequence) ----
  if (t < 8) {
    float v[32];
#pragma unroll
    for (int i = 0; i < 32; ++i) v[i] = chm[t][i];
    float lo = v[0], hi = v[0];
#pragma unroll
    for (int i = 1; i < 32; ++i) { lo = fminf(lo, v[i]); hi = fmaxf(hi, v[i]); }
    for (int it = 0; it < 12; ++it) {
      float mid = 0.5f * (lo + hi);
      int c = 0;
#pragma unroll
      for (int i = 0; i < 32; ++i) c += (v[i] <= mid) ? 1 : 0;
      if (c >= 16) hi = mid; else lo = mid;
    }
    taus[t] = hi;
  }
  __syncthreads();
  float tauv[8];
#pragma unroll
  for (int j = 0; j < 8; ++j) tauv[j] = taus[j];

  // ---- phase B: coalesced rescan, filter into lists ----
  for (int i = 0; i < 32; ++i) {
    int ci = (wid << 11) + (i << 6) + lane;
    float4 cv = P[ci];
#pragma unroll
    for (int j = 0; j < 8; ++j) {
      float d = fmaf(qx[j], cv.x, fmaf(qy[j], cv.y, fmaf(qz[j], cv.z, cv.w)));
      if (d <= tauv[j]) {
        int sl = atomicAdd(&cnt[j], 1);
        if (sl < SLOTS)
          list[j][sl] = ((unsigned long long)fkey_u(d) << 32) | (unsigned)ci;
      }
    }
  }
  __syncthreads();

  // ---- extraction: wave wid handles query pair (2w, 2w+1); stash winners ----
  {
    int qa = wid << 1, qb2 = qa + 1;
    int ca = cnt[qa]; if (ca > SLOTS) ca = SLOTS;
    int cb3 = cnt[qb2]; if (cb3 > SLOTS) cb3 = SLOTS;
    unsigned long long k0a = (lane < ca) ? list[qa][lane] : ~0ULL;
    unsigned long long k1a = (lane + 64 < ca) ? list[qa][lane + 64] : ~0ULL;
    unsigned long long k0b = (lane < cb3) ? list[qb2][lane] : ~0ULL;
    unsigned long long k1b = (lane + 64 < cb3) ? list[qb2][lane + 64] : ~0ULL;
    for (int r = 0; r < 16; ++r) {
      unsigned long long wa = (k0a < k1a) ? k0a : k1a;
      unsigned long long wb = (k0b < k1b) ? k0b : k1b;
      for (int off = 32; off; off >>= 1) {
        unsigned long long oa = shflx64(wa, off);
        unsigned long long ob = shflx64(wb, off);
        if (oa < wa) wa = oa;
        if (ob < wb) wb = ob;
      }
      if (k0a == wa) k0a = ~0ULL; else if (k1a == wa) k1a = ~0ULL;
      if (k0b == wb) k0b = ~0ULL; else if (k1b == wb) k1b = ~0ULL;
      if (lane == 0) {
        int ja = (int)(wa & 0xffffffffu);
        int jb = (int)(wb & 0xffffffffu);
        idxb[((size_t)(b * NN) + q0 + qa) * 16 + r] = ja;
        idxb[((size_t)(b * NN) + q0 + qb2) * 16 + r] = jb;
        win[qa][r] = ja;
        win[qb2][r] = jb;
      }
    }
  }
  __syncthreads();

  // ---- folded rel second moments: threads 0..127, one per (query, rank) ----
  if (t < 128) {
    int qq = t >> 4, r = t & 15;
    int j = win[qq][r];
    int n = q0 + qq;
    float4 pj = P[j];
    float4 pn = P[n];
    float rx = (-0.5f * pj.x) - (-0.5f * pn.x);
    float ry = (-0.5f * pj.y) - (-0.5f * pn.y);
    float rz = (-0.5f * pj.z) - (-0.5f * pn.z);
    float a[9];
    a[0] = rx; a[1] = ry; a[2] = rz;
    a[3] = rx * rx; a[4] = rx * ry; a[5] = rx * rz;
    a[6] = ry * ry; a[7] = ry * rz; a[8] = rz * rz;
#pragma unroll
    for (int m = 0; m < 9; ++m) {
      float v = a[m];
      for (int off = 32; off; off >>= 1) v += __shfl_xor(v, off, 64);
      a[m] = v;
    }
    if (lane == 0) {
#pragma unroll
      for (int m = 0; m < 9; ++m) redst[wid][m] = a[m];
    }
  }
  __syncthreads();
  if (t < 9) {
    float v = redst[0][t] + redst[1][t];
    atomicAdd(&rst[b * 16 + t], v);
  }
}

// ---------------- T1: analytic pos-GN affine ----------------
__global__ __launch_bounds__(256) void t1_kernel(const float* __restrict__ rst,
    const float* __restrict__ pos1_w, const float* __restrict__ pos1_b,
    const float* __restrict__ pos1_g, const float* __restrict__ pos1_be,
    float* __restrict__ s1, float* __restrict__ t1) {
  __shared__ float gsum[16], gsum2[16];
  int t = threadIdx.x;
  if (t < 16) { gsum[t] = 0.f; gsum2[t] = 0.f; }
  __syncthreads();
  int b = t >> 7, c = t & 127;
  const float* S = rst + b * 16;
  const float Minv = 1.0f / (float)(NN * KK);
  float mx = S[0] * Minv, my = S[1] * Minv, mz = S[2] * Minv;
  float Mxx = S[3] * Minv, Mxy = S[4] * Minv, Mxz = S[5] * Minv;
  float Myy = S[6] * Minv, Myz = S[7] * Minv, Mzz = S[8] * Minv;
  float w0 = pos1_w[c * 3], w1 = pos1_w[c * 3 + 1], w2 = pos1_w[c * 3 + 2];
  float bb = pos1_b[c];
  float wm = w0 * mx + w1 * my + w2 * mz;
  float Ey = wm + bb;
  float q = w0 * w0 * Mxx + w1 * w1 * Myy + w2 * w2 * Mzz
          + 2.f * (w0 * w1 * Mxy + w0 * w2 * Mxz + w1 * w2 * Myz);
  float Ey2 = q + 2.f * bb * wm + bb * bb;
  int g = c >> 4;
  atomicAdd(&gsum[b * 8 + g], Ey);
  atomicAdd(&gsum2[b * 8 + g], Ey2);
  __syncthreads();
  float mean = gsum[b * 8 + g] * (1.f / 16.f);
  float var = fmaxf(gsum2[b * 8 + g] * (1.f / 16.f) - mean * mean, 0.f);
  float r = rsqrtf(var + EPSV);
  float sv = pos1_g[c] * r;
  s1[t] = sv;
  t1[t] = fmaf(sv, bb, pos1_be[c] - mean * sv);
}

// ---------------- K3: nf (fp32 VALU) + Aq/Ak/vf via MFMA ----------------
__global__ __launch_bounds__(256) void feat_kernel(
    const float* __restrict__ feat, const float* __restrict__ pre_w, const float* __restrict__ pre_b,
    const __hip_bfloat16* __restrict__ WQ2b, const __hip_bfloat16* __restrict__ WK2b,
    const __hip_bfloat16* __restrict__ WVb, const float* __restrict__ wv_b,
    float* __restrict__ nf, __hip_bfloat16* __restrict__ AqTb,
    __hip_bfloat16* __restrict__ AkTb, __hip_bfloat16* __restrict__ vfTb) {
  int b = blockIdx.x >> 9;
  int n0 = (blockIdx.x & 511) << 4;
  __shared__ float fe[64][20];
  __shared__ float nfs[128][20];
  __shared__ __align__(16) unsigned short zb[16][136];   // bf16 nfs^T [point][ch]
  int t = threadIdx.x;
  int lane = t & 63, wid = t >> 6;
  int l15 = lane & 15, quad = lane >> 4;
  for (int e = t; e < 1024; e += 256) {
    int ci = e >> 4, nn2 = e & 15;
    fe[ci][nn2] = feat[(b * 64 + ci) * NN + n0 + nn2];
  }
  __syncthreads();
  int nq = t & 3, cw = t >> 2;
  {
    float acc[2][4];
#pragma unroll
    for (int m = 0; m < 2; ++m) {
      float bv = pre_b[cw + 64 * m];
      acc[m][0] = bv; acc[m][1] = bv; acc[m][2] = bv; acc[m][3] = bv;
    }
    for (int i = 0; i < 64; ++i) {
      float4 x = *(const float4*)&fe[i][nq << 2];
      float w0 = pre_w[cw * 64 + i];
      float w1 = pre_w[(cw + 64) * 64 + i];
      acc[0][0] = fmaf(w0, x.x, acc[0][0]); acc[0][1] = fmaf(w0, x.y, acc[0][1]);
      acc[0][2] = fmaf(w0, x.z, acc[0][2]); acc[0][3] = fmaf(w0, x.w, acc[0][3]);
      acc[1][0] = fmaf(w1, x.x, acc[1][0]); acc[1][1] = fmaf(w1, x.y, acc[1][1]);
      acc[1][2] = fmaf(w1, x.z, acc[1][2]); acc[1][3] = fmaf(w1, x.w, acc[1][3]);
    }
#pragma unroll
    for (int m = 0; m < 2; ++m) {
      int c = cw + 64 * m;
      float4 v = make_float4(acc[m][0], acc[m][1], acc[m][2], acc[m][3]);
      *(float4*)&nfs[c][nq << 2] = v;
      *(float4*)&nf[(b * 128 + c) * NN + n0 + (nq << 2)] = v;
    }
  }
  __syncthreads();
  // ---- nfs (fp32 [ch][pt]) -> zb (bf16 [pt][ch]) ----
  {
    int cpp = t & 63, pg = t >> 6;
    int cp0 = cpp * 2;
#pragma unroll
    for (int i = 0; i < 4; ++i) {
      int pix = pg * 4 + i;
      *(unsigned*)&zb[pix][cp0] = pack2bf(nfs[cp0][pix], nfs[cp0 + 1][pix]);
    }
  }
  __syncthreads();
  // ---- 3 GEMMs on MFMA ----
  f32x4 acc[3][2];
#pragma unroll
  for (int g = 0; g < 3; ++g)
#pragma unroll
    for (int m2 = 0; m2 < 2; ++m2) acc[g][m2] = (f32x4){0.f, 0.f, 0.f, 0.f};
#pragma unroll
  for (int k0 = 0; k0 < 4; ++k0) {
    short8 bfr = *(const short8*)&zb[l15][k0 * 32 + quad * 8];
#pragma unroll
    for (int m2 = 0; m2 < 2; ++m2) {
      int off = ((wid * 2 + m2) * 16 + l15) * 128 + k0 * 32 + quad * 8;
      short8 aq = *(const short8*)((const unsigned short*)WQ2b + off);
      short8 ak = *(const short8*)((const unsigned short*)WK2b + off);
      short8 av = *(const short8*)((const unsigned short*)WVb + off);
      acc[0][m2] = __builtin_amdgcn_mfma_f32_16x16x32_bf16(aq, bfr, acc[0][m2], 0, 0, 0);
      acc[1][m2] = __builtin_amdgcn_mfma_f32_16x16x32_bf16(ak, bfr, acc[1][m2], 0, 0, 0);
      acc[2][m2] = __builtin_amdgcn_mfma_f32_16x16x32_bf16(av, bfr, acc[2][m2], 0, 0, 0);
    }
  }
  // ---- epilogue ----
  size_t pbase = ((size_t)(b * NN) + n0 + l15) * 128;
#pragma unroll
  for (int m2 = 0; m2 < 2; ++m2) {
    int crow = (wid * 2 + m2) * 16 + quad * 4;
    {
      f32x4 a = acc[0][m2];
      ushort4 o; o.x = f2bf(a[0]); o.y = f2bf(a[1]); o.z = f2bf(a[2]); o.w = f2bf(a[3]);
      *(ushort4*)((unsigned short*)AqTb + pbase + crow) = o;
    }
    {
      f32x4 a = acc[1][m2];
      ushort4 o; o.x = f2bf(a[0]); o.y = f2bf(a[1]); o.z = f2bf(a[2]); o.w = f2bf(a[3]);
      *(ushort4*)((unsigned short*)AkTb + pbase + crow) = o;
    }
    {
      f32x4 a = acc[2][m2];
      ushort4 o;
      o.x = f2bf(a[0] + wv_b[crow]);
      o.y = f2bf(a[1] + wv_b[crow + 1]);
      o.z = f2bf(a[2] + wv_b[crow + 2]);
      o.w = f2bf(a[3] + wv_b[crow + 3]);
      *(ushort4*)((unsigned short*)vfTb + pbase + crow) = o;
    }
  }
}

// ---------------- K5: y = W2@z + Aq - Ak + bias (MFMA), bf16 store + GN partials ----------------
__global__ __launch_bounds__(256) void y_kernel_mfma(const float* __restrict__ xyz,
    const int* __restrict__ idxb, const __hip_bfloat16* __restrict__ AqTb,
    const __hip_bfloat16* __restrict__ AkTb, const __hip_bfloat16* __restrict__ W2b,
    const float* __restrict__ bias_y, const float* __restrict__ pos1_w,
    const float* __restrict__ s1, const float* __restrict__ t1,
    __hip_bfloat16* __restrict__ ybuf, float* __restrict__ partA) {
  int b = blockIdx.x >> 11;
  int pb = (blockIdx.x & 2047) * 4;
  __shared__ __align__(16) __hip_bfloat16 z_s[64][136];
  __shared__ __align__(16) __hip_bfloat16 ak_s[64][136];
  __shared__ __align__(16) float aq_s[4][128];
  __shared__ float rel_s[64][4];
  __shared__ int jj[64];
  __shared__ float gns[8], gns2[8];
  int t = threadIdx.x;
  int lane = t & 63, wid = t >> 6;
  int l15 = lane & 15, quad = lane >> 4;
  if (t < 8) { gns[t] = 0.f; gns2[t] = 0.f; }
  if (t < 64) {
    int n = pb + (t >> 4);
    int j = idxb[(b * NN + pb) * 16 + t];
    jj[t] = j;
    const float* X = xyz + b * 3 * NN;
    rel_s[t][0] = X[j] - X[n];
    rel_s[t][1] = X[NN + j] - X[NN + n];
    rel_s[t][2] = X[2 * NN + j] - X[2 * NN + n];
  }
  for (int e = t; e < 512; e += 256) {
    int pt = e >> 7, c = e & 127;
    aq_s[pt][c] = bf2f(((const unsigned short*)AqTb)[((size_t)(b * NN) + pb + pt) * 128 + c]) + bias_y[c];
  }
  __syncthreads();
  {
    int cpp = t & 63, pg = t >> 6;
    int cp0 = cpp * 2;
    float w00 = pos1_w[cp0 * 3], w01 = pos1_w[cp0 * 3 + 1], w02 = pos1_w[cp0 * 3 + 2];
    float w10 = pos1_w[cp0 * 3 + 3], w11 = pos1_w[cp0 * 3 + 4], w12 = pos1_w[cp0 * 3 + 5];
    float sa = s1[b * 128 + cp0], ta = t1[b * 128 + cp0];
    float sb = s1[b * 128 + cp0 + 1], tb = t1[b * 128 + cp0 + 1];
#pragma unroll
    for (int i = 0; i < 16; ++i) {
      int pix = pg * 16 + i;
      float rx = rel_s[pix][0], ry = rel_s[pix][1], rz = rel_s[pix][2];
      float u0 = fmaf(w02, rz, fmaf(w01, ry, w00 * rx));
      float u1 = fmaf(w12, rz, fmaf(w11, ry, w10 * rx));
      float z0 = fmaf(sa, u0, ta); z0 = (z0 >= 0.f) ? z0 : 0.1f * z0;
      float z1 = fmaf(sb, u1, tb); z1 = (z1 >= 0.f) ? z1 : 0.1f * z1;
      *(unsigned*)&z_s[pix][cp0] = pack2bf(z0, z1);
    }
  }
  for (int e = t; e < 4096; e += 256) {
    int pix = e >> 6, cpp = e & 63;
    *(unsigned*)&ak_s[pix][cpp * 2] =
        *(const unsigned*)((const unsigned short*)AkTb + ((size_t)(b * NN) + jj[pix]) * 128 + cpp * 2);
  }
  short8 afr[2][4];
#pragma unroll
  for (int m2 = 0; m2 < 2; ++m2) {
    int row = (wid * 2 + m2) * 16 + l15;
#pragma unroll
    for (int k0 = 0; k0 < 4; ++k0)
      afr[m2][k0] = *(const short8*)((const unsigned short*)W2b + row * 128 + k0 * 32 + quad * 8);
  }
  __syncthreads();
  f32x4 acc[2][4];
#pragma unroll
  for (int m2 = 0; m2 < 2; ++m2)
#pragma unroll
    for (int nt = 0; nt < 4; ++nt) acc[m2][nt] = (f32x4){0.f, 0.f, 0.f, 0.f};
#pragma unroll
  for (int k0 = 0; k0 < 4; ++k0) {
#pragma unroll
    for (int nt = 0; nt < 4; ++nt) {
      short8 bfr = *(const short8*)&z_s[nt * 16 + l15][k0 * 32 + quad * 8];
      acc[0][nt] = __builtin_amdgcn_mfma_f32_16x16x32_bf16(afr[0][k0], bfr, acc[0][nt], 0, 0, 0);
      acc[1][nt] = __builtin_amdgcn_mfma_f32_16x16x32_bf16(afr[1][k0], bfr, acc[1][nt], 0, 0, 0);
    }
  }
  float lsum[2] = {0.f, 0.f}, lsum2[2] = {0.f, 0.f};
#pragma unroll
  for (int m2 = 0; m2 < 2; ++m2) {
    int c0 = (wid * 2 + m2) * 16 + quad * 4;
#pragma unroll
    for (int nt = 0; nt < 4; ++nt) {
      int pix = nt * 16 + l15;
      ushort4 au = *(ushort4*)&ak_s[pix][c0];
      float4 aq = *(float4*)&aq_s[nt][c0];
      f32x4 a = acc[m2][nt];
      float v0 = a[0] + aq.x - bf2f(au.x);
      float v1 = a[1] + aq.y - bf2f(au.y);
      float v2 = a[2] + aq.z - bf2f(au.z);
      float v3 = a[3] + aq.w - bf2f(au.w);
      lsum[m2] += (v0 + v1) + (v2 + v3);
      lsum2[m2] += fmaf(v0, v0, fmaf(v1, v1, fmaf(v2, v2, v3 * v3)));
      ushort4 yo;
      yo.x = f2bf(v0); yo.y = f2bf(v1); yo.z = f2bf(v2); yo.w = f2bf(v3);
      *(ushort4*)&ak_s[pix][c0] = yo;
    }
  }
#pragma unroll
  for (int m2 = 0; m2 < 2; ++m2) {
    float s = lsum[m2], s2 = lsum2[m2];
    for (int msk = 1; msk < 64; msk <<= 1) {
      s += __shfl_xor(s, msk);
      s2 += __shfl_xor(s2, msk);
    }
    if (lane == 0) {
      atomicAdd(&gns[wid * 2 + m2], s);
      atomicAdd(&gns2[wid * 2 + m2], s2);
    }
  }
  __syncthreads();
  size_t ybase = ((size_t)(b * NN) + pb) * 16;
  unsigned short* yb = (unsigned short*)ybuf;
  for (int e = t; e < 4096; e += 256) {
    int pix = e >> 6, cpp = e & 63;
    *(unsigned*)(yb + (ybase + pix) * 128 + cpp * 2) = *(unsigned*)&ak_s[pix][cpp * 2];
  }
  if (t < 8) {
    partA[(size_t)t * 4096 + blockIdx.x] = gns[t];
    partA[(size_t)(8 + t) * 4096 + blockIdx.x] = gns2[t];
  }
}

// ---------------- T3a: reduce GN partials [16][4096] -> red[32] ----------------
__global__ __launch_bounds__(256) void gnred_kernel(const float* __restrict__ part,
                                                    float* __restrict__ red) {
  int k = blockIdx.x;
  int pb = k >> 4, idx = k & 15;
  const float* p = part + (size_t)idx * 4096 + pb * 2048;
  float s = 0.f;
  for (int i = threadIdx.x; i < 2048; i += 256) s += p[i];
  __shared__ float rs[4];
  int lane = threadIdx.x & 63, wid = threadIdx.x >> 6;
  for (int off = 32; off; off >>= 1) s += __shfl_xor(s, off);
  if (lane == 0) rs[wid] = s;
  __syncthreads();
  if (threadIdx.x == 0) red[k] = rs[0] + rs[1] + rs[2] + rs[3];
}

// ---------------- K7: scores=A2@h (MFMA) + per-thread softmax (inline gnaff) ----------------
__global__ __launch_bounds__(256) void att_out_kernel(const __hip_bfloat16* __restrict__ ybuf,
    const int* __restrict__ idxb, const float* __restrict__ redA,
    const float* __restrict__ att1_g, const float* __restrict__ att1_be,
    const __hip_bfloat16* __restrict__ A2b, const __hip_bfloat16* __restrict__ vfTb,
    const float* __restrict__ nf, const float* __restrict__ PWT, const float* __restrict__ post_b,
    float* __restrict__ out2, float* __restrict__ partP) {
  int b = blockIdx.x >> 11;
  int pb = (blockIdx.x & 2047) * 4;
  __shared__ __align__(16) union HS {
    unsigned short h[64][136];
    float sc[2][128][17];
  } hs;
  __shared__ __align__(16) __hip_bfloat16 v_s[64][136];
  __shared__ __align__(16) float opre[4][132];
  __shared__ int jj[64];
  __shared__ float gns[8], gns2[8];
  int t = threadIdx.x;
  int lane = t & 63, wid = t >> 6;
  int l15 = lane & 15, quad = lane >> 4;
  if (t < 8) { gns[t] = 0.f; gns2[t] = 0.f; }
  if (t < 64) jj[t] = idxb[(b * NN + pb) * 16 + t];
  __syncthreads();
  size_t ybase = ((size_t)(b * NN) + pb) * 16;
  const unsigned short* yb = (const unsigned short*)ybuf;
  {
    int cpp = t & 63, pg = t >> 6;
    int c0 = cpp * 2;
    const float Minv = 1.0f / 2097152.0f;
    int g = c0 >> 4;
    float S = redA[b * 16 + g], S2v = redA[b * 16 + 8 + g];
    float mean = S * Minv;
    float var = fmaxf(S2v * Minv - mean * mean, 0.f);
    float r = rsqrtf(var + EPSV);
    float sa = att1_g[c0] * r;
    float ta = att1_be[c0] - mean * sa;
    float sb = att1_g[c0 + 1] * r;
    float tb = att1_be[c0 + 1] - mean * sb;
#pragma unroll
    for (int i = 0; i < 16; ++i) {
      int pix = pg * 16 + i;
      unsigned u = *(const unsigned*)(yb + (ybase + pix) * 128 + c0);
      float y0 = bf2f((unsigned short)(u & 0xffff));
      float y1 = bf2f((unsigned short)(u >> 16));
      float h0 = fmaf(sa, y0, ta); h0 = (h0 >= 0.f) ? h0 : 0.1f * h0;
      float h1 = fmaf(sb, y1, tb); h1 = (h1 >= 0.f) ? h1 : 0.1f * h1;
      *(unsigned*)&hs.h[pix][c0] = pack2bf(h0, h1);
    }
  }
  for (int e = t; e < 4096; e += 256) {
    int pix = e >> 6, cpp = e & 63;
    *(unsigned*)&v_s[pix][cpp * 2] =
        *(const unsigned*)((const unsigned short*)vfTb + ((size_t)(b * NN) + jj[pix]) * 128 + cpp * 2);
  }
  short8 afr[2][4];
#pragma unroll
  for (int m2 = 0; m2 < 2; ++m2) {
    int row = (wid * 2 + m2) * 16 + l15;
#pragma unroll
    for (int k0 = 0; k0 < 4; ++k0)
      afr[m2][k0] = *(const short8*)((const unsigned short*)A2b + row * 128 + k0 * 32 + quad * 8);
  }
  __syncthreads();
  f32x4 acc[2][4];
#pragma unroll
  for (int m2 = 0; m2 < 2; ++m2)
#pragma unroll
    for (int nt = 0; nt < 4; ++nt) acc[m2][nt] = (f32x4){0.f, 0.f, 0.f, 0.f};
#pragma unroll
  for (int k0 = 0; k0 < 4; ++k0) {
#pragma unroll
    for (int nt = 0; nt < 4; ++nt) {
      short8 bfr = *(const short8*)&hs.h[nt * 16 + l15][k0 * 32 + quad * 8];
      acc[0][nt] = __builtin_amdgcn_mfma_f32_16x16x32_bf16(afr[0][k0], bfr, acc[0][nt], 0, 0, 0);
      acc[1][nt] = __builtin_amdgcn_mfma_f32_16x16x32_bf16(afr[1][k0], bfr, acc[1][nt], 0, 0, 0);
    }
  }
  int pidx = t >> 7;
  int cch = t & 127;
#pragma unroll
  for (int pass = 0; pass < 2; ++pass) {
    __syncthreads();
#pragma unroll
    for (int ntl = 0; ntl < 2; ++ntl) {
      int nt = pass * 2 + ntl;
#pragma unroll
      for (int m2 = 0; m2 < 2; ++m2) {
        int cb = (wid * 2 + m2) * 16 + quad * 4;
        f32x4 a = acc[m2][nt];
#pragma unroll
        for (int r = 0; r < 4; ++r) hs.sc[ntl][cb + r][l15] = a[r];
      }
    }
    __syncthreads();
    {
      int p = pass * 2 + pidx;
      float nfv = nf[(size_t)(b * 128 + cch) * NN + pb + p];
      const float* srow = hs.sc[pidx][cch];
      float sv[16];
#pragma unroll
      for (int k = 0; k < 16; ++k) sv[k] = srow[k];
      float mx = sv[0];
#pragma unroll
      for (int k = 1; k < 16; ++k) mx = fmaxf(mx, sv[k]);
      float sm = 0.f, dot = 0.f;
#pragma unroll
      for (int k = 0; k < 16; ++k) {
        float e = __expf(sv[k] - mx);
        sm += e;
        float vv = bf2f(*(const unsigned short*)&v_s[p * 16 + k][cch]);
        dot = fmaf(e, vv, dot);
      }
      opre[p][cch] = dot / sm + nfv;
    }
  }
  __syncthreads();
  {
    int c = t & 127, g = t >> 7;
    float a0 = post_b[c], a1 = a0;
    for (int cp = 0; cp < 128; ++cp) {
      float w = PWT[cp * 128 + c];
      a0 = fmaf(w, opre[g * 2][cp], a0);
      a1 = fmaf(w, opre[g * 2 + 1][cp], a1);
    }
    out2[(size_t)(b * 128 + c) * NN + pb + g * 2] = a0;
    out2[(size_t)(b * 128 + c) * NN + pb + g * 2 + 1] = a1;
    atomicAdd(&gns[c >> 4], a0 + a1);
    atomicAdd(&gns2[c >> 4], fmaf(a0, a0, a1 * a1));
  }
  __syncthreads();
  if (t < 8) {
    partP[(size_t)t * 4096 + blockIdx.x] = gns[t];
    partP[(size_t)(8 + t) * 4096 + blockIdx.x] = gns2[t];
  }
}

// ---------------- K9: final normalize + lrelu (gnaff inline, float4) ----------------
__global__ __launch_bounds__(256) void final_kernel(const float* __restrict__ out2,
    const float* __restrict__ redP, const float* __restrict__ post_g,
    const float* __restrict__ post_be, float* __restrict__ out) {
  int e4 = blockIdx.x * 256 + threadIdx.x;   // 0..524287
  int base = e4 * 4;
  int c = (base >> 13) & 127, b = base >> 20;
  const float Minv = 1.0f / 131072.0f;
  int g = c >> 4;
  float S = redP[b * 16 + g], S2 = redP[b * 16 + 8 + g];
  float mean = S * Minv;
  float var = fmaxf(S2 * Minv - mean * mean, 0.f);
  float r = rsqrtf(var + EPSV);
  float sv = post_g[c] * r;
  float tv = post_be[c] - mean * sv;
  float4 x = *(const float4*)&out2[base];
  float4 o;
  o.x = fmaf(sv, x.x, tv); o.x = (o.x >= 0.f) ? o.x : 0.1f * o.x;
  o.y = fmaf(sv, x.y, tv); o.y = (o.y >= 0.f) ? o.y : 0.1f * o.y;
  o.z = fmaf(sv, x.z, tv); o.z = (o.z >= 0.f) ? o.z : 0.1f * o.z;
  o.w = fmaf(sv, x.w, tv); o.w = (o.w >= 0.f) ? o.w : 0.1f * o.w;
  *(float4*)&((float*)out)[base] = o;
}

// ---------------- launch ----------------
extern "C" void kernel_launch(void* const* d_in, const int* in_sizes, int n_in,
                              void* d_out, int out_size, void* d_ws, size_t ws_size,
                              hipStream_t stream) {
  (void)in_sizes; (void)n_in; (void)out_size; (void)ws_size;
  const float* xyz     = (const float*)d_in[0];
  const float* feat    = (const float*)d_in[1];
  const float* pre_w   = (const float*)d_in[2];
  const float* pre_b   = (const float*)d_in[3];
  const float* wq_w    = (const float*)d_in[4];
  const float* wq_b    = (const float*)d_in[5];
  const float* wk_w    = (const float*)d_in[6];
  const float* wk_b    = (const float*)d_in[7];
  const float* wv_w    = (const float*)d_in[8];
  const float* wv_b    = (const float*)d_in[9];
  const float* pos1_w  = (const float*)d_in[10];
  const float* pos1_b  = (const float*)d_in[11];
  const float* pos1_g  = (const float*)d_in[12];
  const float* pos1_be = (const float*)d_in[13];
  const float* pos2_w  = (const float*)d_in[14];
  const float* pos2_b  = (const float*)d_in[15];
  const float* att1_w  = (const float*)d_in[16];
  const float* att1_b  = (const float*)d_in[17];
  const float* att1_g  = (const float*)d_in[18];
  const float* att1_be = (const float*)d_in[19];
  const float* att2_w  = (const float*)d_in[20];
  // d_in[21] = att2_b: constant over k -> cancels in softmax
  const float* post_w  = (const float*)d_in[22];
  const float* post_b  = (const float*)d_in[23];
  const float* post_g  = (const float*)d_in[24];
  const float* post_be = (const float*)d_in[25];

  float* W = (float*)d_ws;
  int* idxb = (int*)d_ws;
  float* nf   = W + OFF_NF;
  float* out2 = W + OFF_OUT2;
  __hip_bfloat16* ybuf = (__hip_bfloat16*)(W + OFF_Y);
  __hip_bfloat16* AqTb = (__hip_bfloat16*)(W + OFF_AQB);
  __hip_bfloat16* AkTb = (__hip_bfloat16*)(W + OFF_AKB);
  __hip_bfloat16* vfTb = (__hip_bfloat16*)(W + OFF_VFB);
  __hip_bfloat16* WQ2B = (__hip_bfloat16*)(W + OFF_WQ2);          // bf16 128x128
  __hip_bfloat16* WVB  = (__hip_bfloat16*)(W + OFF_WQ2 + 8192);   // bf16 128x128
  __hip_bfloat16* WK2B = (__hip_bfloat16*)(W + OFF_WK2);          // bf16 128x128
  float* PWT  = W + OFF_PWT;
  __hip_bfloat16* W2b = (__hip_bfloat16*)(W + OFF_W2B);
  __hip_bfloat16* A2b = (__hip_bfloat16*)(W + OFF_A2B);
  float* BY   = W + OFF_BY;
  float* RST  = W + OFF_RST;
  float* REDA = W + OFF_REDA;
  float* REDP = W + OFF_REDP;
  float* S1 = W + OFF_S1; float* T1 = W + OFF_T1;
  float4* PTS4 = (float4*)(W + OFF_PTS4);
  float* PARTA = W + OFF_PTA;
  float* PARTP = W + OFF_PTP;

  hipMemsetAsync(RST, 0, 32 * sizeof(float), stream);

  prep_weights<<<258, 128, 0, stream>>>(att1_w, wq_w, wk_w, pos2_w, att2_w, post_w, wv_w,
                                        wq_b, wk_b, pos2_b, att1_b, xyz,
                                        WQ2B, WK2B, WVB, W2b, A2b, PWT, BY, PTS4);
  knn_kernel<<<2048, 256, 0, stream>>>(PTS4, idxb, RST);
  t1_kernel<<<1, 256, 0, stream>>>(RST, pos1_w, pos1_b, pos1_g, pos1_be, S1, T1);
  feat_kernel<<<1024, 256, 0, stream>>>(feat, pre_w, pre_b, WQ2B, WK2B, WVB, wv_b,
                                        nf, AqTb, AkTb, vfTb);
  y_kernel_mfma<<<4096, 256, 0, stream>>>(xyz, idxb, AqTb, AkTb, W2b, BY, pos1_w, S1, T1, ybuf, PARTA);
  gnred_kernel<<<32, 256, 0, stream>>>(PARTA, REDA);
  att_out_kernel<<<4096, 256, 0, stream>>>(ybuf, idxb, REDA, att1_g, att1_be,
                                           A2b, vfTb, nf, PWT, post_b, out2, PARTP);
  gnred_kernel<<<32, 256, 0, stream>>>(PARTP, REDP);
  final_kernel<<<2048, 256, 0, stream>>>(out2, REDP, post_g, post_be, (float*)d_out);
}

// Round 17
// 354.453 us; speedup vs baseline: 1.0086x; 1.0086x over previous
//
#include <hip/hip_runtime.h>
#include <hip/hip_bf16.h>

#define BB 2
#define NN 8192
#define CC 128
#define CIN_ 64
#define KK 16
#define EPSV 1e-5f

typedef __attribute__((ext_vector_type(8))) short short8;
typedef __attribute__((ext_vector_type(4))) float f32x4;

// ---------------- workspace layout (float-element offsets) ----------------
// idx (int, B*N*K) occupies [0, 262144)
static const size_t OFF_NF   = 262144;                 // fp32 B*C*N
static const size_t OFF_OUT2 = OFF_NF  + 2097152;      // fp32 B*C*N
static const size_t OFF_Y    = OFF_OUT2 + 2097152;     // bf16 [B*N*K][C]
static const size_t OFF_AQB  = OFF_Y   + 16777216;     // bf16 [B*N][C]
static const size_t OFF_AKB  = OFF_AQB + 1048576;
static const size_t OFF_VFB  = OFF_AKB + 1048576;
static const size_t OFF_WQ2  = OFF_VFB + 1048576;      // bf16 WQ2b [0,8192) + bf16 WVb [8192,16384)
static const size_t OFF_WK2  = OFF_WQ2 + 16384;        // bf16 WK2b
static const size_t OFF_PWT  = OFF_WK2 + 16384;        // fp32 post_w^T [cp][c]
static const size_t OFF_W2B  = OFF_PWT + 16384;        // bf16 (att1@pos2) [c][cp]
static const size_t OFF_A2B  = OFF_W2B + 8192;         // bf16 att2_w [c][cp]
static const size_t OFF_BY   = OFF_A2B + 8192;         // 128
static const size_t OFF_RST  = OFF_BY  + 128;          // B*16 (9 used)  [zeroed]
static const size_t OFF_REDA = OFF_RST + 32;           // 32 reduced GN sums (y)
static const size_t OFF_REDP = OFF_REDA + 32;          // 32 reduced GN sums (post)
static const size_t OFF_S1   = OFF_REDP + 32;
static const size_t OFF_T1   = OFF_S1 + 256;
static const size_t OFF_S2   = OFF_T1 + 256;           // (unused)
static const size_t OFF_T2   = OFF_S2 + 256;
static const size_t OFF_S3   = OFF_T2 + 256;
static const size_t OFF_T3   = OFF_S3 + 256;
static const size_t OFF_PTS4 = OFF_T3 + 256;           // float4 B*N -> 65536 floats
static const size_t OFF_PTA  = OFF_PTS4 + 65536;       // GN partials y: [16][4096]
static const size_t OFF_PTP  = OFF_PTA + 65536;        // GN partials post: [16][4096]

// ---------------- helpers ----------------
__device__ __forceinline__ unsigned fkey_u(float d) {
  unsigned u = __float_as_uint(d);
  return (u & 0x80000000u) ? ~u : (u | 0x80000000u);
}
__device__ __forceinline__ unsigned long long shflx64(unsigned long long v, int m) {
  int lo = __shfl_xor((int)(unsigned)(v & 0xffffffffu), m, 64);
  int hi = __shfl_xor((int)(unsigned)(v >> 32), m, 64);
  return ((unsigned long long)(unsigned)hi << 32) | (unsigned)lo;
}
__device__ __forceinline__ float bf2f(unsigned short u) {
  return __uint_as_float((unsigned)u << 16);
}
__device__ __forceinline__ unsigned short f2bf(float f) {
  __hip_bfloat16 h = __float2bfloat16(f);
  unsigned short r;
  __builtin_memcpy(&r, &h, 2);
  return r;
}
__device__ __forceinline__ unsigned pack2bf(float a, float b) {
  return (unsigned)f2bf(a) | ((unsigned)f2bf(b) << 16);
}

// ---------------- T2: weight prep + pts4 (fused) ----------------
__global__ __launch_bounds__(128) void prep_weights(
    const float* __restrict__ att1_w, const float* __restrict__ wq_w, const float* __restrict__ wk_w,
    const float* __restrict__ pos2_w, const float* __restrict__ att2_w, const float* __restrict__ post_w,
    const float* __restrict__ wv_w,
    const float* __restrict__ wq_b, const float* __restrict__ wk_b, const float* __restrict__ pos2_b,
    const float* __restrict__ att1_b, const float* __restrict__ xyz,
    __hip_bfloat16* __restrict__ WQ2b, __hip_bfloat16* __restrict__ WK2b,
    __hip_bfloat16* __restrict__ WVb, __hip_bfloat16* __restrict__ W2b,
    __hip_bfloat16* __restrict__ A2b, float* __restrict__ PWT, float* __restrict__ bias_y,
    float4* __restrict__ pts4) {
  int blk = blockIdx.x, t = threadIdx.x;
  if (blk < 128) {
    int c = blk;
    __shared__ float row[128];
    row[t] = att1_w[c * 128 + t];
    __syncthreads();
    float sq = 0.f, sk = 0.f, sp = 0.f;
    for (int m = 0; m < 128; ++m) {
      float r = row[m];
      sq = fmaf(r, wq_w[m * 128 + t], sq);
      sk = fmaf(r, wk_w[m * 128 + t], sk);
      sp = fmaf(r, pos2_w[m * 128 + t], sp);
    }
    WQ2b[c * 128 + t] = __float2bfloat16(sq);
    WK2b[c * 128 + t] = __float2bfloat16(sk);
    W2b[c * 128 + t] = __float2bfloat16(sp);   // row-major [c][cp]
  } else if (blk == 128) {
    for (int e = t; e < 16384; e += 128) {
      int c = e >> 7, cp = e & 127;
      A2b[e] = __float2bfloat16(att2_w[e]);    // [c][cp] row-major
      PWT[cp * 128 + c] = post_w[e];           // fp32 transposed
      WVb[e] = __float2bfloat16(wv_w[e]);      // [c][k] row-major
    }
  } else if (blk == 129) {
    float s = att1_b[t];
    for (int m = 0; m < 128; ++m)
      s = fmaf(att1_w[t * 128 + m], wq_b[m] - wk_b[m] + pos2_b[m], s);
    bias_y[t] = s;
  } else {
    int e = (blk - 130) * 128 + t;             // 0..16383
    int b = e >> 13, n = e & 8191;
    const float* X = xyz + b * 3 * NN;
    float x = X[n], y = X[NN + n], z = X[2 * NN + n];
    pts4[e] = make_float4(-2.0f * x, -2.0f * y, -2.0f * z, fmaf(z, z, fmaf(y, y, x * x)));
  }
}

// ---------------- K1: kNN (R18/R15 form, 16 q/block, 1024 blocks) + folded rel-stats ----------------
// R16's 8q/2048blk variant REFUTED the occupancy hypothesis: occupancy 37->52% but
// VALUBusy flat (~53%) and dur 90->97 µs (doubled candidate traffic, less ILP).
// This 16q form is the floor of 8 structural variants (90 µs); keeping it final.
#define SLOTS 96
__global__ __launch_bounds__(256) void knn_kernel(const float4* __restrict__ pts4,
                                                  int* __restrict__ idxb,
                                                  float* __restrict__ rst) {
  __shared__ unsigned long long list[16][SLOTS];   // 12 KB
  __shared__ float chm[16][33];
  __shared__ float taus[16];
  __shared__ int cnt[16];
  __shared__ int win[16][16];                      // selected neighbor indices
  __shared__ float redst[4][9];
  int t = threadIdx.x;
  int wid = t >> 6, lane = t & 63;
  int blk = blockIdx.x;              // 0..1023
  int b = blk >> 9;                  // 512 blocks per batch
  int q0 = (blk & 511) << 4;         // 16 queries per block
  const float4* P = pts4 + b * NN;
  if (t < 16) cnt[t] = 0;
  float qx[16], qy[16], qz[16];
#pragma unroll
  for (int j = 0; j < 16; ++j) {
    float4 qv = P[q0 + j];
    qx[j] = -0.5f * qv.x; qy[j] = -0.5f * qv.y; qz[j] = -0.5f * qv.z;
  }

  // ---- phase A: 8 lanes/chunk, 8 chunks in parallel; wave wid owns chunks [8w,8w+8) ----
  {
    int g = lane >> 3, s = lane & 7;
    const float4* Pc = P + (wid << 11) + (g << 8);
    float mn[16];
#pragma unroll
    for (int j = 0; j < 16; ++j) mn[j] = 3.4e38f;
    for (int i = 0; i < 32; i += 2) {
      float4 c0 = Pc[(i << 3) + s];
      float4 c1 = Pc[((i + 1) << 3) + s];
#pragma unroll
      for (int j = 0; j < 16; ++j) {
        float d0 = fmaf(qx[j], c0.x, fmaf(qy[j], c0.y, fmaf(qz[j], c0.z, c0.w)));
        float d1 = fmaf(qx[j], c1.x, fmaf(qy[j], c1.y, fmaf(qz[j], c1.z, c1.w)));
        mn[j] = fminf(mn[j], fminf(d0, d1));
      }
    }
#pragma unroll
    for (int off = 1; off < 8; off <<= 1)
#pragma unroll
      for (int j = 0; j < 16; ++j) mn[j] = fminf(mn[j], __shfl_xor(mn[j], off));
    if (s == 0) {
#pragma unroll
      for (int j = 0; j < 16; ++j) chm[j][(wid << 3) + g] = mn[j];
    }
  }
  __syncthreads();

  // ---- tau ----
  if (t < 16) {
    float v[32];
#pragma unroll
    for (int i = 0; i < 32; ++i) v[i] = chm[t][i];
    float lo = v[0], hi = v[0];
#pragma unroll
    for (int i = 1; i < 32; ++i) { lo = fminf(lo, v[i]); hi = fmaxf(hi, v[i]); }
    for (int it = 0; it < 12; ++it) {
      float mid = 0.5f * (lo + hi);
      int c = 0;
#pragma unroll
      for (int i = 0; i < 32; ++i) c += (v[i] <= mid) ? 1 : 0;
      if (c >= 16) hi = mid; else lo = mid;
    }
    taus[t] = hi;
  }
  __syncthreads();
  float tauv[16];
#pragma unroll
  for (int j = 0; j < 16; ++j) tauv[j] = taus[j];

  // ---- phase B: coalesced rescan, filter into lists ----
  for (int i = 0; i < 32; ++i) {
    int ci = (wid << 11) + (i << 6) + lane;
    float4 cv = P[ci];
#pragma unroll
    for (int j = 0; j < 16; ++j) {
      float d = fmaf(qx[j], cv.x, fmaf(qy[j], cv.y, fmaf(qz[j], cv.z, cv.w)));
      if (d <= tauv[j]) {
        int sl = atomicAdd(&cnt[j], 1);
        if (sl < SLOTS)
          list[j][sl] = ((unsigned long long)fkey_u(d) << 32) | (unsigned)ci;
      }
    }
  }
  __syncthreads();

  // ---- extraction (stashes winners to win[][]) ----
  for (int pp = 0; pp < 2; ++pp) {
    int qa = (wid << 2) + pp * 2, qb2 = qa + 1;
    int ca = cnt[qa]; if (ca > SLOTS) ca = SLOTS;
    int cb3 = cnt[qb2]; if (cb3 > SLOTS) cb3 = SLOTS;
    unsigned long long k0a = (lane < ca) ? list[qa][lane] : ~0ULL;
    unsigned long long k1a = (lane + 64 < ca) ? list[qa][lane + 64] : ~0ULL;
    unsigned long long k0b = (lane < cb3) ? list[qb2][lane] : ~0ULL;
    unsigned long long k1b = (lane + 64 < cb3) ? list[qb2][lane + 64] : ~0ULL;
    for (int r = 0; r < 16; ++r) {
      unsigned long long wa = (k0a < k1a) ? k0a : k1a;
      unsigned long long wb = (k0b < k1b) ? k0b : k1b;
      for (int off = 32; off; off >>= 1) {
        unsigned long long oa = shflx64(wa, off);
        unsigned long long ob = shflx64(wb, off);
        if (oa < wa) wa = oa;
        if (ob < wb) wb = ob;
      }
      if (k0a == wa) k0a = ~0ULL; else if (k1a == wa) k1a = ~0ULL;
      if (k0b == wb) k0b = ~0ULL; else if (k1b == wb) k1b = ~0ULL;
      if (lane == 0) {
        int ja = (int)(wa & 0xffffffffu);
        int jb = (int)(wb & 0xffffffffu);
        idxb[((size_t)(b * NN) + q0 + qa) * 16 + r] = ja;
        idxb[((size_t)(b * NN) + q0 + qb2) * 16 + r] = jb;
        win[qa][r] = ja;
        win[qb2][r] = jb;
      }
    }
  }
  __syncthreads();

  // ---- folded rel second moments: one thread per (query, rank) ----
  {
    int qq = t >> 4, r = t & 15;
    int j = win[qq][r];
    int n = q0 + qq;
    float4 pj = P[j];
    float4 pn = P[n];
    float rx = (-0.5f * pj.x) - (-0.5f * pn.x);
    float ry = (-0.5f * pj.y) - (-0.5f * pn.y);
    float rz = (-0.5f * pj.z) - (-0.5f * pn.z);
    float a[9];
    a[0] = rx; a[1] = ry; a[2] = rz;
    a[3] = rx * rx; a[4] = rx * ry; a[5] = rx * rz;
    a[6] = ry * ry; a[7] = ry * rz; a[8] = rz * rz;
#pragma unroll
    for (int m = 0; m < 9; ++m) {
      float v = a[m];
      for (int off = 32; off; off >>= 1) v += __shfl_xor(v, off, 64);
      a[m] = v;
    }
    if (lane == 0) {
#pragma unroll
      for (int m = 0; m < 9; ++m) redst[wid][m] = a[m];
    }
  }
  __syncthreads();
  if (t < 9) {
    float v = redst[0][t] + redst[1][t] + redst[2][t] + redst[3][t];
    atomicAdd(&rst[b * 16 + t], v);
  }
}

// ---------------- T1: analytic pos-GN affine ----------------
__global__ __launch_bounds__(256) void t1_kernel(const float* __restrict__ rst,
    const float* __restrict__ pos1_w, const float* __restrict__ pos1_b,
    const float* __restrict__ pos1_g, const float* __restrict__ pos1_be,
    float* __restrict__ s1, float* __restrict__ t1) {
  __shared__ float gsum[16], gsum2[16];
  int t = threadIdx.x;
  if (t < 16) { gsum[t] = 0.f; gsum2[t] = 0.f; }
  __syncthreads();
  int b = t >> 7, c = t & 127;
  const float* S = rst + b * 16;
  const float Minv = 1.0f / (float)(NN * KK);
  float mx = S[0] * Minv, my = S[1] * Minv, mz = S[2] * Minv;
  float Mxx = S[3] * Minv, Mxy = S[4] * Minv, Mxz = S[5] * Minv;
  float Myy = S[6] * Minv, Myz = S[7] * Minv, Mzz = S[8] * Minv;
  float w0 = pos1_w[c * 3], w1 = pos1_w[c * 3 + 1], w2 = pos1_w[c * 3 + 2];
  float bb = pos1_b[c];
  float wm = w0 * mx + w1 * my + w2 * mz;
  float Ey = wm + bb;
  float q = w0 * w0 * Mxx + w1 * w1 * Myy + w2 * w2 * Mzz
          + 2.f * (w0 * w1 * Mxy + w0 * w2 * Mxz + w1 * w2 * Myz);
  float Ey2 = q + 2.f * bb * wm + bb * bb;
  int g = c >> 4;
  atomicAdd(&gsum[b * 8 + g], Ey);
  atomicAdd(&gsum2[b * 8 + g], Ey2);
  __syncthreads();
  float mean = gsum[b * 8 + g] * (1.f / 16.f);
  float var = fmaxf(gsum2[b * 8 + g] * (1.f / 16.f) - mean * mean, 0.f);
  float r = rsqrtf(var + EPSV);
  float sv = pos1_g[c] * r;
  s1[t] = sv;
  t1[t] = fmaf(sv, bb, pos1_be[c] - mean * sv);
}

// ---------------- K3: nf (fp32 VALU) + Aq/Ak/vf via MFMA ----------------
__global__ __launch_bounds__(256) void feat_kernel(
    const float* __restrict__ feat, const float* __restrict__ pre_w, const float* __restrict__ pre_b,
    const __hip_bfloat16* __restrict__ WQ2b, const __hip_bfloat16* __restrict__ WK2b,
    const __hip_bfloat16* __restrict__ WVb, const float* __restrict__ wv_b,
    float* __restrict__ nf, __hip_bfloat16* __restrict__ AqTb,
    __hip_bfloat16* __restrict__ AkTb, __hip_bfloat16* __restrict__ vfTb) {
  int b = blockIdx.x >> 9;
  int n0 = (blockIdx.x & 511) << 4;
  __shared__ float fe[64][20];
  __shared__ float nfs[128][20];
  __shared__ __align__(16) unsigned short zb[16][136];   // bf16 nfs^T [point][ch]
  int t = threadIdx.x;
  int lane = t & 63, wid = t >> 6;
  int l15 = lane & 15, quad = lane >> 4;
  for (int e = t; e < 1024; e += 256) {
    int ci = e >> 4, nn2 = e & 15;
    fe[ci][nn2] = feat[(b * 64 + ci) * NN + n0 + nn2];
  }
  __syncthreads();
  int nq = t & 3, cw = t >> 2;
  {
    float acc[2][4];
#pragma unroll
    for (int m = 0; m < 2; ++m) {
      float bv = pre_b[cw + 64 * m];
      acc[m][0] = bv; acc[m][1] = bv; acc[m][2] = bv; acc[m][3] = bv;
    }
    for (int i = 0; i < 64; ++i) {
      float4 x = *(const float4*)&fe[i][nq << 2];
      float w0 = pre_w[cw * 64 + i];
      float w1 = pre_w[(cw + 64) * 64 + i];
      acc[0][0] = fmaf(w0, x.x, acc[0][0]); acc[0][1] = fmaf(w0, x.y, acc[0][1]);
      acc[0][2] = fmaf(w0, x.z, acc[0][2]); acc[0][3] = fmaf(w0, x.w, acc[0][3]);
      acc[1][0] = fmaf(w1, x.x, acc[1][0]); acc[1][1] = fmaf(w1, x.y, acc[1][1]);
      acc[1][2] = fmaf(w1, x.z, acc[1][2]); acc[1][3] = fmaf(w1, x.w, acc[1][3]);
    }
#pragma unroll
    for (int m = 0; m < 2; ++m) {
      int c = cw + 64 * m;
      float4 v = make_float4(acc[m][0], acc[m][1], acc[m][2], acc[m][3]);
      *(float4*)&nfs[c][nq << 2] = v;
      *(float4*)&nf[(b * 128 + c) * NN + n0 + (nq << 2)] = v;
    }
  }
  __syncthreads();
  // ---- nfs (fp32 [ch][pt]) -> zb (bf16 [pt][ch]) ----
  {
    int cpp = t & 63, pg = t >> 6;
    int cp0 = cpp * 2;
#pragma unroll
    for (int i = 0; i < 4; ++i) {
      int pix = pg * 4 + i;
      *(unsigned*)&zb[pix][cp0] = pack2bf(nfs[cp0][pix], nfs[cp0 + 1][pix]);
    }
  }
  __syncthreads();
  // ---- 3 GEMMs on MFMA ----
  f32x4 acc[3][2];
#pragma unroll
  for (int g = 0; g < 3; ++g)
#pragma unroll
    for (int m2 = 0; m2 < 2; ++m2) acc[g][m2] = (f32x4){0.f, 0.f, 0.f, 0.f};
#pragma unroll
  for (int k0 = 0; k0 < 4; ++k0) {
    short8 bfr = *(const short8*)&zb[l15][k0 * 32 + quad * 8];
#pragma unroll
    for (int m2 = 0; m2 < 2; ++m2) {
      int off = ((wid * 2 + m2) * 16 + l15) * 128 + k0 * 32 + quad * 8;
      short8 aq = *(const short8*)((const unsigned short*)WQ2b + off);
      short8 ak = *(const short8*)((const unsigned short*)WK2b + off);
      short8 av = *(const short8*)((const unsigned short*)WVb + off);
      acc[0][m2] = __builtin_amdgcn_mfma_f32_16x16x32_bf16(aq, bfr, acc[0][m2], 0, 0, 0);
      acc[1][m2] = __builtin_amdgcn_mfma_f32_16x16x32_bf16(ak, bfr, acc[1][m2], 0, 0, 0);
      acc[2][m2] = __builtin_amdgcn_mfma_f32_16x16x32_bf16(av, bfr, acc[2][m2], 0, 0, 0);
    }
  }
  // ---- epilogue ----
  size_t pbase = ((size_t)(b * NN) + n0 + l15) * 128;
#pragma unroll
  for (int m2 = 0; m2 < 2; ++m2) {
    int crow = (wid * 2 + m2) * 16 + quad * 4;
    {
      f32x4 a = acc[0][m2];
      ushort4 o; o.x = f2bf(a[0]); o.y = f2bf(a[1]); o.z = f2bf(a[2]); o.w = f2bf(a[3]);
      *(ushort4*)((unsigned short*)AqTb + pbase + crow) = o;
    }
    {
      f32x4 a = acc[1][m2];
      ushort4 o; o.x = f2bf(a[0]); o.y = f2bf(a[1]); o.z = f2bf(a[2]); o.w = f2bf(a[3]);
      *(ushort4*)((unsigned short*)AkTb + pbase + crow) = o;
    }
    {
      f32x4 a = acc[2][m2];
      ushort4 o;
      o.x = f2bf(a[0] + wv_b[crow]);
      o.y = f2bf(a[1] + wv_b[crow + 1]);
      o.z = f2bf(a[2] + wv_b[crow + 2]);
      o.w = f2bf(a[3] + wv_b[crow + 3]);
      *(ushort4*)((unsigned short*)vfTb + pbase + crow) = o;
    }
  }
}

// ---------------- K5: y = W2@z + Aq - Ak + bias (MFMA), bf16 store + GN partials ----------------
__global__ __launch_bounds__(256) void y_kernel_mfma(const float* __restrict__ xyz,
    const int* __restrict__ idxb, const __hip_bfloat16* __restrict__ AqTb,
    const __hip_bfloat16* __restrict__ AkTb, const __hip_bfloat16* __restrict__ W2b,
    const float* __restrict__ bias_y, const float* __restrict__ pos1_w,
    const float* __restrict__ s1, const float* __restrict__ t1,
    __hip_bfloat16* __restrict__ ybuf, float* __restrict__ partA) {
  int b = blockIdx.x >> 11;
  int pb = (blockIdx.x & 2047) * 4;
  __shared__ __align__(16) __hip_bfloat16 z_s[64][136];
  __shared__ __align__(16) __hip_bfloat16 ak_s[64][136];
  __shared__ __align__(16) float aq_s[4][128];
  __shared__ float rel_s[64][4];
  __shared__ int jj[64];
  __shared__ float gns[8], gns2[8];
  int t = threadIdx.x;
  int lane = t & 63, wid = t >> 6;
  int l15 = lane & 15, quad = lane >> 4;
  if (t < 8) { gns[t] = 0.f; gns2[t] = 0.f; }
  if (t < 64) {
    int n = pb + (t >> 4);
    int j = idxb[(b * NN + pb) * 16 + t];
    jj[t] = j;
    const float* X = xyz + b * 3 * NN;
    rel_s[t][0] = X[j] - X[n];
    rel_s[t][1] = X[NN + j] - X[NN + n];
    rel_s[t][2] = X[2 * NN + j] - X[2 * NN + n];
  }
  for (int e = t; e < 512; e += 256) {
    int pt = e >> 7, c = e & 127;
    aq_s[pt][c] = bf2f(((const unsigned short*)AqTb)[((size_t)(b * NN) + pb + pt) * 128 + c]) + bias_y[c];
  }
  __syncthreads();
  {
    int cpp = t & 63, pg = t >> 6;
    int cp0 = cpp * 2;
    float w00 = pos1_w[cp0 * 3], w01 = pos1_w[cp0 * 3 + 1], w02 = pos1_w[cp0 * 3 + 2];
    float w10 = pos1_w[cp0 * 3 + 3], w11 = pos1_w[cp0 * 3 + 4], w12 = pos1_w[cp0 * 3 + 5];
    float sa = s1[b * 128 + cp0], ta = t1[b * 128 + cp0];
    float sb = s1[b * 128 + cp0 + 1], tb = t1[b * 128 + cp0 + 1];
#pragma unroll
    for (int i = 0; i < 16; ++i) {
      int pix = pg * 16 + i;
      float rx = rel_s[pix][0], ry = rel_s[pix][1], rz = rel_s[pix][2];
      float u0 = fmaf(w02, rz, fmaf(w01, ry, w00 * rx));
      float u1 = fmaf(w12, rz, fmaf(w11, ry, w10 * rx));
      float z0 = fmaf(sa, u0, ta); z0 = (z0 >= 0.f) ? z0 : 0.1f * z0;
      float z1 = fmaf(sb, u1, tb); z1 = (z1 >= 0.f) ? z1 : 0.1f * z1;
      *(unsigned*)&z_s[pix][cp0] = pack2bf(z0, z1);
    }
  }
  for (int e = t; e < 4096; e += 256) {
    int pix = e >> 6, cpp = e & 63;
    *(unsigned*)&ak_s[pix][cpp * 2] =
        *(const unsigned*)((const unsigned short*)AkTb + ((size_t)(b * NN) + jj[pix]) * 128 + cpp * 2);
  }
  short8 afr[2][4];
#pragma unroll
  for (int m2 = 0; m2 < 2; ++m2) {
    int row = (wid * 2 + m2) * 16 + l15;
#pragma unroll
    for (int k0 = 0; k0 < 4; ++k0)
      afr[m2][k0] = *(const short8*)((const unsigned short*)W2b + row * 128 + k0 * 32 + quad * 8);
  }
  __syncthreads();
  f32x4 acc[2][4];
#pragma unroll
  for (int m2 = 0; m2 < 2; ++m2)
#pragma unroll
    for (int nt = 0; nt < 4; ++nt) acc[m2][nt] = (f32x4){0.f, 0.f, 0.f, 0.f};
#pragma unroll
  for (int k0 = 0; k0 < 4; ++k0) {
#pragma unroll
    for (int nt = 0; nt < 4; ++nt) {
      short8 bfr = *(const short8*)&z_s[nt * 16 + l15][k0 * 32 + quad * 8];
      acc[0][nt] = __builtin_amdgcn_mfma_f32_16x16x32_bf16(afr[0][k0], bfr, acc[0][nt], 0, 0, 0);
      acc[1][nt] = __builtin_amdgcn_mfma_f32_16x16x32_bf16(afr[1][k0], bfr, acc[1][nt], 0, 0, 0);
    }
  }
  float lsum[2] = {0.f, 0.f}, lsum2[2] = {0.f, 0.f};
#pragma unroll
  for (int m2 = 0; m2 < 2; ++m2) {
    int c0 = (wid * 2 + m2) * 16 + quad * 4;
#pragma unroll
    for (int nt = 0; nt < 4; ++nt) {
      int pix = nt * 16 + l15;
      ushort4 au = *(ushort4*)&ak_s[pix][c0];
      float4 aq = *(float4*)&aq_s[nt][c0];
      f32x4 a = acc[m2][nt];
      float v0 = a[0] + aq.x - bf2f(au.x);
      float v1 = a[1] + aq.y - bf2f(au.y);
      float v2 = a[2] + aq.z - bf2f(au.z);
      float v3 = a[3] + aq.w - bf2f(au.w);
      lsum[m2] += (v0 + v1) + (v2 + v3);
      lsum2[m2] += fmaf(v0, v0, fmaf(v1, v1, fmaf(v2, v2, v3 * v3)));
      ushort4 yo;
      yo.x = f2bf(v0); yo.y = f2bf(v1); yo.z = f2bf(v2); yo.w = f2bf(v3);
      *(ushort4*)&ak_s[pix][c0] = yo;
    }
  }
#pragma unroll
  for (int m2 = 0; m2 < 2; ++m2) {
    float s = lsum[m2], s2 = lsum2[m2];
    for (int msk = 1; msk < 64; msk <<= 1) {
      s += __shfl_xor(s, msk);
      s2 += __shfl_xor(s2, msk);
    }
    if (lane == 0) {
      atomicAdd(&gns[wid * 2 + m2], s);
      atomicAdd(&gns2[wid * 2 + m2], s2);
    }
  }
  __syncthreads();
  size_t ybase = ((size_t)(b * NN) + pb) * 16;
  unsigned short* yb = (unsigned short*)ybuf;
  for (int e = t; e < 4096; e += 256) {
    int pix = e >> 6, cpp = e & 63;
    *(unsigned*)(yb + (ybase + pix) * 128 + cpp * 2) = *(unsigned*)&ak_s[pix][cpp * 2];
  }
  if (t < 8) {
    partA[(size_t)t * 4096 + blockIdx.x] = gns[t];
    partA[(size_t)(8 + t) * 4096 + blockIdx.x] = gns2[t];
  }
}

// ---------------- T3a: reduce GN partials [16][4096] -> red[32] ----------------
__global__ __launch_bounds__(256) void gnred_kernel(const float* __restrict__ part,
                                                    float* __restrict__ red) {
  int k = blockIdx.x;
  int pb = k >> 4, idx = k & 15;
  const float* p = part + (size_t)idx * 4096 + pb * 2048;
  float s = 0.f;
  for (int i = threadIdx.x; i < 2048; i += 256) s += p[i];
  __shared__ float rs[4];
  int lane = threadIdx.x & 63, wid = threadIdx.x >> 6;
  for (int off = 32; off; off >>= 1) s += __shfl_xor(s, off);
  if (lane == 0) rs[wid] = s;
  __syncthreads();
  if (threadIdx.x == 0) red[k] = rs[0] + rs[1] + rs[2] + rs[3];
}

// ---------------- K7: scores=A2@h (MFMA) + per-thread softmax (inline gnaff) ----------------
__global__ __launch_bounds__(256) void att_out_kernel(const __hip_bfloat16* __restrict__ ybuf,
    const int* __restrict__ idxb, const float* __restrict__ redA,
    const float* __restrict__ att1_g, const float* __restrict__ att1_be,
    const __hip_bfloat16* __restrict__ A2b, const __hip_bfloat16* __restrict__ vfTb,
    const float* __restrict__ nf, const float* __restrict__ PWT, const float* __restrict__ post_b,
    float* __restrict__ out2, float* __restrict__ partP) {
  int b = blockIdx.x >> 11;
  int pb = (blockIdx.x & 2047) * 4;
  __shared__ __align__(16) union HS {
    unsigned short h[64][136];
    float sc[2][128][17];
  } hs;
  __shared__ __align__(16) __hip_bfloat16 v_s[64][136];
  __shared__ __align__(16) float opre[4][132];
  __shared__ int jj[64];
  __shared__ float gns[8], gns2[8];
  int t = threadIdx.x;
  int lane = t & 63, wid = t >> 6;
  int l15 = lane & 15, quad = lane >> 4;
  if (t < 8) { gns[t] = 0.f; gns2[t] = 0.f; }
  if (t < 64) jj[t] = idxb[(b * NN + pb) * 16 + t];
  __syncthreads();
  size_t ybase = ((size_t)(b * NN) + pb) * 16;
  const unsigned short* yb = (const unsigned short*)ybuf;
  {
    int cpp = t & 63, pg = t >> 6;
    int c0 = cpp * 2;
    const float Minv = 1.0f / 2097152.0f;
    int g = c0 >> 4;
    float S = redA[b * 16 + g], S2v = redA[b * 16 + 8 + g];
    float mean = S * Minv;
    float var = fmaxf(S2v * Minv - mean * mean, 0.f);
    float r = rsqrtf(var + EPSV);
    float sa = att1_g[c0] * r;
    float ta = att1_be[c0] - mean * sa;
    float sb = att1_g[c0 + 1] * r;
    float tb = att1_be[c0 + 1] - mean * sb;
#pragma unroll
    for (int i = 0; i < 16; ++i) {
      int pix = pg * 16 + i;
      unsigned u = *(const unsigned*)(yb + (ybase + pix) * 128 + c0);
      float y0 = bf2f((unsigned short)(u & 0xffff));
      float y1 = bf2f((unsigned short)(u >> 16));
      float h0 = fmaf(sa, y0, ta); h0 = (h0 >= 0.f) ? h0 : 0.1f * h0;
      float h1 = fmaf(sb, y1, tb); h1 = (h1 >= 0.f) ? h1 : 0.1f * h1;
      *(unsigned*)&hs.h[pix][c0] = pack2bf(h0, h1);
    }
  }
  for (int e = t; e < 4096; e += 256) {
    int pix = e >> 6, cpp = e & 63;
    *(unsigned*)&v_s[pix][cpp * 2] =
        *(const unsigned*)((const unsigned short*)vfTb + ((size_t)(b * NN) + jj[pix]) * 128 + cpp * 2);
  }
  short8 afr[2][4];
#pragma unroll
  for (int m2 = 0; m2 < 2; ++m2) {
    int row = (wid * 2 + m2) * 16 + l15;
#pragma unroll
    for (int k0 = 0; k0 < 4; ++k0)
      afr[m2][k0] = *(const short8*)((const unsigned short*)A2b + row * 128 + k0 * 32 + quad * 8);
  }
  __syncthreads();
  f32x4 acc[2][4];
#pragma unroll
  for (int m2 = 0; m2 < 2; ++m2)
#pragma unroll
    for (int nt = 0; nt < 4; ++nt) acc[m2][nt] = (f32x4){0.f, 0.f, 0.f, 0.f};
#pragma unroll
  for (int k0 = 0; k0 < 4; ++k0) {
#pragma unroll
    for (int nt = 0; nt < 4; ++nt) {
      short8 bfr = *(const short8*)&hs.h[nt * 16 + l15][k0 * 32 + quad * 8];
      acc[0][nt] = __builtin_amdgcn_mfma_f32_16x16x32_bf16(afr[0][k0], bfr, acc[0][nt], 0, 0, 0);
      acc[1][nt] = __builtin_amdgcn_mfma_f32_16x16x32_bf16(afr[1][k0], bfr, acc[1][nt], 0, 0, 0);
    }
  }
  int pidx = t >> 7;
  int cch = t & 127;
#pragma unroll
  for (int pass = 0; pass < 2; ++pass) {
    __syncthreads();
#pragma unroll
    for (int ntl = 0; ntl < 2; ++ntl) {
      int nt = pass * 2 + ntl;
#pragma unroll
      for (int m2 = 0; m2 < 2; ++m2) {
        int cb = (wid * 2 + m2) * 16 + quad * 4;
        f32x4 a = acc[m2][nt];
#pragma unroll
        for (int r = 0; r < 4; ++r) hs.sc[ntl][cb + r][l15] = a[r];
      }
    }
    __syncthreads();
    {
      int p = pass * 2 + pidx;
      float nfv = nf[(size_t)(b * 128 + cch) * NN + pb + p];
      const float* srow = hs.sc[pidx][cch];
      float sv[16];
#pragma unroll
      for (int k = 0; k < 16; ++k) sv[k] = srow[k];
      float mx = sv[0];
#pragma unroll
      for (int k = 1; k < 16; ++k) mx = fmaxf(mx, sv[k]);
      float sm = 0.f, dot = 0.f;
#pragma unroll
      for (int k = 0; k < 16; ++k) {
        float e = __expf(sv[k] - mx);
        sm += e;
        float vv = bf2f(*(const unsigned short*)&v_s[p * 16 + k][cch]);
        dot = fmaf(e, vv, dot);
      }
      opre[p][cch] = dot / sm + nfv;
    }
  }
  __syncthreads();
  {
    int c = t & 127, g = t >> 7;
    float a0 = post_b[c], a1 = a0;
    for (int cp = 0; cp < 128; ++cp) {
      float w = PWT[cp * 128 + c];
      a0 = fmaf(w, opre[g * 2][cp], a0);
      a1 = fmaf(w, opre[g * 2 + 1][cp], a1);
    }
    out2[(size_t)(b * 128 + c) * NN + pb + g * 2] = a0;
    out2[(size_t)(b * 128 + c) * NN + pb + g * 2 + 1] = a1;
    atomicAdd(&gns[c >> 4], a0 + a1);
    atomicAdd(&gns2[c >> 4], fmaf(a0, a0, a1 * a1));
  }
  __syncthreads();
  if (t < 8) {
    partP[(size_t)t * 4096 + blockIdx.x] = gns[t];
    partP[(size_t)(8 + t) * 4096 + blockIdx.x] = gns2[t];
  }
}

// ---------------- K9: final normalize + lrelu (gnaff inline, float4) ----------------
__global__ __launch_bounds__(256) void final_kernel(const float* __restrict__ out2,
    const float* __restrict__ redP, const float* __restrict__ post_g,
    const float* __restrict__ post_be, float* __restrict__ out) {
  int e4 = blockIdx.x * 256 + threadIdx.x;   // 0..524287
  int base = e4 * 4;
  int c = (base >> 13) & 127, b = base >> 20;
  const float Minv = 1.0f / 131072.0f;
  int g = c >> 4;
  float S = redP[b * 16 + g], S2 = redP[b * 16 + 8 + g];
  float mean = S * Minv;
  float var = fmaxf(S2 * Minv - mean * mean, 0.f);
  float r = rsqrtf(var + EPSV);
  float sv = post_g[c] * r;
  float tv = post_be[c] - mean * sv;
  float4 x = *(const float4*)&out2[base];
  float4 o;
  o.x = fmaf(sv, x.x, tv); o.x = (o.x >= 0.f) ? o.x : 0.1f * o.x;
  o.y = fmaf(sv, x.y, tv); o.y = (o.y >= 0.f) ? o.y : 0.1f * o.y;
  o.z = fmaf(sv, x.z, tv); o.z = (o.z >= 0.f) ? o.z : 0.1f * o.z;
  o.w = fmaf(sv, x.w, tv); o.w = (o.w >= 0.f) ? o.w : 0.1f * o.w;
  *(float4*)&((float*)out)[base] = o;
}

// ---------------- launch ----------------
extern "C" void kernel_launch(void* const* d_in, const int* in_sizes, int n_in,
                              void* d_out, int out_size, void* d_ws, size_t ws_size,
                              hipStream_t stream) {
  (void)in_sizes; (void)n_in; (void)out_size; (void)ws_size;
  const float* xyz     = (const float*)d_in[0];
  const float* feat    = (const float*)d_in[1];
  const float* pre_w   = (const float*)d_in[2];
  const float* pre_b   = (const float*)d_in[3];
  const float* wq_w    = (const float*)d_in[4];
  const float* wq_b    = (const float*)d_in[5];
  const float* wk_w    = (const float*)d_in[6];
  const float* wk_b    = (const float*)d_in[7];
  const float* wv_w    = (const float*)d_in[8];
  const float* wv_b    = (const float*)d_in[9];
  const float* pos1_w  = (const float*)d_in[10];
  const float* pos1_b  = (const float*)d_in[11];
  const float* pos1_g  = (const float*)d_in[12];
  const float* pos1_be = (const float*)d_in[13];
  const float* pos2_w  = (const float*)d_in[14];
  const float* pos2_b  = (const float*)d_in[15];
  const float* att1_w  = (const float*)d_in[16];
  const float* att1_b  = (const float*)d_in[17];
  const float* att1_g  = (const float*)d_in[18];
  const float* att1_be = (const float*)d_in[19];
  const float* att2_w  = (const float*)d_in[20];
  // d_in[21] = att2_b: constant over k -> cancels in softmax
  const float* post_w  = (const float*)d_in[22];
  const float* post_b  = (const float*)d_in[23];
  const float* post_g  = (const float*)d_in[24];
  const float* post_be = (const float*)d_in[25];

  float* W = (float*)d_ws;
  int* idxb = (int*)d_ws;
  float* nf   = W + OFF_NF;
  float* out2 = W + OFF_OUT2;
  __hip_bfloat16* ybuf = (__hip_bfloat16*)(W + OFF_Y);
  __hip_bfloat16* AqTb = (__hip_bfloat16*)(W + OFF_AQB);
  __hip_bfloat16* AkTb = (__hip_bfloat16*)(W + OFF_AKB);
  __hip_bfloat16* vfTb = (__hip_bfloat16*)(W + OFF_VFB);
  __hip_bfloat16* WQ2B = (__hip_bfloat16*)(W + OFF_WQ2);          // bf16 128x128
  __hip_bfloat16* WVB  = (__hip_bfloat16*)(W + OFF_WQ2 + 8192);   // bf16 128x128
  __hip_bfloat16* WK2B = (__hip_bfloat16*)(W + OFF_WK2);          // bf16 128x128
  float* PWT  = W + OFF_PWT;
  __hip_bfloat16* W2b = (__hip_bfloat16*)(W + OFF_W2B);
  __hip_bfloat16* A2b = (__hip_bfloat16*)(W + OFF_A2B);
  float* BY   = W + OFF_BY;
  float* RST  = W + OFF_RST;
  float* REDA = W + OFF_REDA;
  float* REDP = W + OFF_REDP;
  float* S1 = W + OFF_S1; float* T1 = W + OFF_T1;
  float4* PTS4 = (float4*)(W + OFF_PTS4);
  float* PARTA = W + OFF_PTA;
  float* PARTP = W + OFF_PTP;

  hipMemsetAsync(RST, 0, 32 * sizeof(float), stream);

  prep_weights<<<258, 128, 0, stream>>>(att1_w, wq_w, wk_w, pos2_w, att2_w, post_w, wv_w,
                                        wq_b, wk_b, pos2_b, att1_b, xyz,
                                        WQ2B, WK2B, WVB, W2b, A2b, PWT, BY, PTS4);
  knn_kernel<<<1024, 256, 0, stream>>>(PTS4, idxb, RST);
  t1_kernel<<<1, 256, 0, stream>>>(RST, pos1_w, pos1_b, pos1_g, pos1_be, S1, T1);
  feat_kernel<<<1024, 256, 0, stream>>>(feat, pre_w, pre_b, WQ2B, WK2B, WVB, wv_b,
                                        nf, AqTb, AkTb, vfTb);
  y_kernel_mfma<<<4096, 256, 0, stream>>>(xyz, idxb, AqTb, AkTb, W2b, BY, pos1_w, S1, T1, ybuf, PARTA);
  gnred_kernel<<<32, 256, 0, stream>>>(PARTA, REDA);
  att_out_kernel<<<4096, 256, 0, stream>>>(ybuf, idxb, REDA, att1_g, att1_be,
                                           A2b, vfTb, nf, PWT, post_b, out2, PARTP);
  gnred_kernel<<<32, 256, 0, stream>>>(PARTP, REDP);
  final_kernel<<<2048, 256, 0, stream>>>(out2, REDP, post_g, post_be, (float*)d_out);
}

// Round 18
// 351.974 us; speedup vs baseline: 1.0157x; 1.0070x over previous
//
#include <hip/hip_runtime.h>
#include <hip/hip_bf16.h>

#define BB 2
#define NN 8192
#define CC 128
#define CIN_ 64
#define KK 16
#define EPSV 1e-5f

typedef __attribute__((ext_vector_type(8))) short short8;
typedef __attribute__((ext_vector_type(4))) float f32x4;

// ---------------- workspace layout (float-element offsets) ----------------
// idx (int, B*N*K) occupies [0, 262144)
static const size_t OFF_NF   = 262144;                 // fp32 B*C*N
static const size_t OFF_OUT2 = OFF_NF  + 2097152;      // fp32 B*C*N
static const size_t OFF_Y    = OFF_OUT2 + 2097152;     // bf16 [B*N*K][C]
static const size_t OFF_AQB  = OFF_Y   + 16777216;     // bf16 [B*N][C]
static const size_t OFF_AKB  = OFF_AQB + 1048576;
static const size_t OFF_VFB  = OFF_AKB + 1048576;
static const size_t OFF_WQ2  = OFF_VFB + 1048576;      // bf16 WQ2b [0,8192) + bf16 WVb [8192,16384)
static const size_t OFF_WK2  = OFF_WQ2 + 16384;        // bf16 WK2b
static const size_t OFF_PWT  = OFF_WK2 + 16384;        // fp32 post_w^T [cp][c]
static const size_t OFF_W2B  = OFF_PWT + 16384;        // bf16 (att1@pos2) [c][cp]
static const size_t OFF_A2B  = OFF_W2B + 8192;         // bf16 att2_w [c][cp]
static const size_t OFF_BY   = OFF_A2B + 8192;         // 128
static const size_t OFF_RST  = OFF_BY  + 128;          // B*16 (9 used)  [zeroed]
static const size_t OFF_REDA = OFF_RST + 32;           // 32 reduced GN sums (y)
static const size_t OFF_REDP = OFF_REDA + 32;          // 32 reduced GN sums (post)
static const size_t OFF_S1   = OFF_REDP + 32;
static const size_t OFF_T1   = OFF_S1 + 256;
static const size_t OFF_S2   = OFF_T1 + 256;           // (unused)
static const size_t OFF_T2   = OFF_S2 + 256;
static const size_t OFF_S3   = OFF_T2 + 256;
static const size_t OFF_T3   = OFF_S3 + 256;
static const size_t OFF_PTS4 = OFF_T3 + 256;           // float4 B*N -> 65536 floats
static const size_t OFF_PTA  = OFF_PTS4 + 65536;       // GN partials y: [16][4096]
static const size_t OFF_PTP  = OFF_PTA + 65536;        // GN partials post: [16][4096]

// ---------------- helpers ----------------
__device__ __forceinline__ unsigned fkey_u(float d) {
  unsigned u = __float_as_uint(d);
  return (u & 0x80000000u) ? ~u : (u | 0x80000000u);
}
__device__ __forceinline__ unsigned long long shflx64(unsigned long long v, int m) {
  int lo = __shfl_xor((int)(unsigned)(v & 0xffffffffu), m, 64);
  int hi = __shfl_xor((int)(unsigned)(v >> 32), m, 64);
  return ((unsigned long long)(unsigned)hi << 32) | (unsigned)lo;
}
__device__ __forceinline__ float bf2f(unsigned short u) {
  return __uint_as_float((unsigned)u << 16);
}
__device__ __forceinline__ unsigned short f2bf(float f) {
  __hip_bfloat16 h = __float2bfloat16(f);
  unsigned short r;
  __builtin_memcpy(&r, &h, 2);
  return r;
}
__device__ __forceinline__ unsigned pack2bf(float a, float b) {
  return (unsigned)f2bf(a) | ((unsigned)f2bf(b) << 16);
}

// ---------------- T2: weight prep + pts4 (fused) ----------------
__global__ __launch_bounds__(128) void prep_weights(
    const float* __restrict__ att1_w, const float* __restrict__ wq_w, const float* __restrict__ wk_w,
    const float* __restrict__ pos2_w, const float* __restrict__ att2_w, const float* __restrict__ post_w,
    const float* __restrict__ wv_w,
    const float* __restrict__ wq_b, const float* __restrict__ wk_b, const float* __restrict__ pos2_b,
    const float* __restrict__ att1_b, const float* __restrict__ xyz,
    __hip_bfloat16* __restrict__ WQ2b, __hip_bfloat16* __restrict__ WK2b,
    __hip_bfloat16* __restrict__ WVb, __hip_bfloat16* __restrict__ W2b,
    __hip_bfloat16* __restrict__ A2b, float* __restrict__ PWT, float* __restrict__ bias_y,
    float4* __restrict__ pts4) {
  int blk = blockIdx.x, t = threadIdx.x;
  if (blk < 128) {
    int c = blk;
    __shared__ float row[128];
    row[t] = att1_w[c * 128 + t];
    __syncthreads();
    float sq = 0.f, sk = 0.f, sp = 0.f;
    for (int m = 0; m < 128; ++m) {
      float r = row[m];
      sq = fmaf(r, wq_w[m * 128 + t], sq);
      sk = fmaf(r, wk_w[m * 128 + t], sk);
      sp = fmaf(r, pos2_w[m * 128 + t], sp);
    }
    WQ2b[c * 128 + t] = __float2bfloat16(sq);
    WK2b[c * 128 + t] = __float2bfloat16(sk);
    W2b[c * 128 + t] = __float2bfloat16(sp);   // row-major [c][cp]
  } else if (blk == 128) {
    for (int e = t; e < 16384; e += 128) {
      int c = e >> 7, cp = e & 127;
      A2b[e] = __float2bfloat16(att2_w[e]);    // [c][cp] row-major
      PWT[cp * 128 + c] = post_w[e];           // fp32 transposed
      WVb[e] = __float2bfloat16(wv_w[e]);      // [c][k] row-major
    }
  } else if (blk == 129) {
    float s = att1_b[t];
    for (int m = 0; m < 128; ++m)
      s = fmaf(att1_w[t * 128 + m], wq_b[m] - wk_b[m] + pos2_b[m], s);
    bias_y[t] = s;
  } else {
    int e = (blk - 130) * 128 + t;             // 0..16383
    int b = e >> 13, n = e & 8191;
    const float* X = xyz + b * 3 * NN;
    float x = X[n], y = X[NN + n], z = X[2 * NN + n];
    pts4[e] = make_float4(-2.0f * x, -2.0f * y, -2.0f * z, fmaf(z, z, fmaf(y, y, x * x)));
  }
}

// ---------------- K1: kNN (R18/R15 form) + folded rel-stats + R17b chunk culling ----------------
// R17b: phase B skips (chunk, query) pairs where chm[q][ch] > tau[q] — every
// distance in that chunk is >= chm > tau, so it provably contains no hit. By
// construction only ~16 of 32 chunks pass per query -> ~50% of phase-B math
// skipped. Identical hit set -> identical selected indices.
#define SLOTS 96
__global__ __launch_bounds__(256) void knn_kernel(const float4* __restrict__ pts4,
                                                  int* __restrict__ idxb,
                                                  float* __restrict__ rst) {
  __shared__ unsigned long long list[16][SLOTS];   // 12 KB
  __shared__ float chm[16][33];
  __shared__ float taus[16];
  __shared__ int cnt[16];
  __shared__ int win[16][16];                      // selected neighbor indices
  __shared__ float redst[4][9];
  int t = threadIdx.x;
  int wid = t >> 6, lane = t & 63;
  int blk = blockIdx.x;              // 0..1023
  int b = blk >> 9;                  // 512 blocks per batch
  int q0 = (blk & 511) << 4;         // 16 queries per block
  const float4* P = pts4 + b * NN;
  if (t < 16) cnt[t] = 0;
  float qx[16], qy[16], qz[16];
#pragma unroll
  for (int j = 0; j < 16; ++j) {
    float4 qv = P[q0 + j];
    qx[j] = -0.5f * qv.x; qy[j] = -0.5f * qv.y; qz[j] = -0.5f * qv.z;
  }

  // ---- phase A: 8 lanes/chunk, 8 chunks in parallel; wave wid owns chunks [8w,8w+8) ----
  {
    int g = lane >> 3, s = lane & 7;
    const float4* Pc = P + (wid << 11) + (g << 8);
    float mn[16];
#pragma unroll
    for (int j = 0; j < 16; ++j) mn[j] = 3.4e38f;
    for (int i = 0; i < 32; i += 2) {
      float4 c0 = Pc[(i << 3) + s];
      float4 c1 = Pc[((i + 1) << 3) + s];
#pragma unroll
      for (int j = 0; j < 16; ++j) {
        float d0 = fmaf(qx[j], c0.x, fmaf(qy[j], c0.y, fmaf(qz[j], c0.z, c0.w)));
        float d1 = fmaf(qx[j], c1.x, fmaf(qy[j], c1.y, fmaf(qz[j], c1.z, c1.w)));
        mn[j] = fminf(mn[j], fminf(d0, d1));
      }
    }
#pragma unroll
    for (int off = 1; off < 8; off <<= 1)
#pragma unroll
      for (int j = 0; j < 16; ++j) mn[j] = fminf(mn[j], __shfl_xor(mn[j], off));
    if (s == 0) {
#pragma unroll
      for (int j = 0; j < 16; ++j) chm[j][(wid << 3) + g] = mn[j];
    }
  }
  __syncthreads();

  // ---- tau ----
  if (t < 16) {
    float v[32];
#pragma unroll
    for (int i = 0; i < 32; ++i) v[i] = chm[t][i];
    float lo = v[0], hi = v[0];
#pragma unroll
    for (int i = 1; i < 32; ++i) { lo = fminf(lo, v[i]); hi = fmaxf(hi, v[i]); }
    for (int it = 0; it < 12; ++it) {
      float mid = 0.5f * (lo + hi);
      int c = 0;
#pragma unroll
      for (int i = 0; i < 32; ++i) c += (v[i] <= mid) ? 1 : 0;
      if (c >= 16) hi = mid; else lo = mid;
    }
    taus[t] = hi;
  }
  __syncthreads();
  float tauv[16];
#pragma unroll
  for (int j = 0; j < 16; ++j) tauv[j] = taus[j];

  // ---- phase B: chunk-culled rescan, filter into lists ----
  for (int ch = 0; ch < 8; ++ch) {
    int gch = (wid << 3) + ch;
    unsigned qmask = 0;
#pragma unroll
    for (int j = 0; j < 16; ++j)
      if (chm[j][gch] <= tauv[j]) qmask |= (1u << j);
    if (qmask == 0) continue;                 // uniform across wave -> scalar skip
#pragma unroll 1
    for (int i = 0; i < 4; ++i) {
      int ci = (wid << 11) + (ch << 8) + (i << 6) + lane;
      float4 cv = P[ci];
#pragma unroll
      for (int j = 0; j < 16; ++j) {
        if (qmask & (1u << j)) {
          float d = fmaf(qx[j], cv.x, fmaf(qy[j], cv.y, fmaf(qz[j], cv.z, cv.w)));
          if (d <= tauv[j]) {
            int sl = atomicAdd(&cnt[j], 1);
            if (sl < SLOTS)
              list[j][sl] = ((unsigned long long)fkey_u(d) << 32) | (unsigned)ci;
          }
        }
      }
    }
  }
  __syncthreads();

  // ---- extraction (stashes winners to win[][]) ----
  for (int pp = 0; pp < 2; ++pp) {
    int qa = (wid << 2) + pp * 2, qb2 = qa + 1;
    int ca = cnt[qa]; if (ca > SLOTS) ca = SLOTS;
    int cb3 = cnt[qb2]; if (cb3 > SLOTS) cb3 = SLOTS;
    unsigned long long k0a = (lane < ca) ? list[qa][lane] : ~0ULL;
    unsigned long long k1a = (lane + 64 < ca) ? list[qa][lane + 64] : ~0ULL;
    unsigned long long k0b = (lane < cb3) ? list[qb2][lane] : ~0ULL;
    unsigned long long k1b = (lane + 64 < cb3) ? list[qb2][lane + 64] : ~0ULL;
    for (int r = 0; r < 16; ++r) {
      unsigned long long wa = (k0a < k1a) ? k0a : k1a;
      unsigned long long wb = (k0b < k1b) ? k0b : k1b;
      for (int off = 32; off; off >>= 1) {
        unsigned long long oa = shflx64(wa, off);
        unsigned long long ob = shflx64(wb, off);
        if (oa < wa) wa = oa;
        if (ob < wb) wb = ob;
      }
      if (k0a == wa) k0a = ~0ULL; else if (k1a == wa) k1a = ~0ULL;
      if (k0b == wb) k0b = ~0ULL; else if (k1b == wb) k1b = ~0ULL;
      if (lane == 0) {
        int ja = (int)(wa & 0xffffffffu);
        int jb = (int)(wb & 0xffffffffu);
        idxb[((size_t)(b * NN) + q0 + qa) * 16 + r] = ja;
        idxb[((size_t)(b * NN) + q0 + qb2) * 16 + r] = jb;
        win[qa][r] = ja;
        win[qb2][r] = jb;
      }
    }
  }
  __syncthreads();

  // ---- folded rel second moments: one thread per (query, rank) ----
  {
    int qq = t >> 4, r = t & 15;
    int j = win[qq][r];
    int n = q0 + qq;
    float4 pj = P[j];
    float4 pn = P[n];
    float rx = (-0.5f * pj.x) - (-0.5f * pn.x);
    float ry = (-0.5f * pj.y) - (-0.5f * pn.y);
    float rz = (-0.5f * pj.z) - (-0.5f * pn.z);
    float a[9];
    a[0] = rx; a[1] = ry; a[2] = rz;
    a[3] = rx * rx; a[4] = rx * ry; a[5] = rx * rz;
    a[6] = ry * ry; a[7] = ry * rz; a[8] = rz * rz;
#pragma unroll
    for (int m = 0; m < 9; ++m) {
      float v = a[m];
      for (int off = 32; off; off >>= 1) v += __shfl_xor(v, off, 64);
      a[m] = v;
    }
    if (lane == 0) {
#pragma unroll
      for (int m = 0; m < 9; ++m) redst[wid][m] = a[m];
    }
  }
  __syncthreads();
  if (t < 9) {
    float v = redst[0][t] + redst[1][t] + redst[2][t] + redst[3][t];
    atomicAdd(&rst[b * 16 + t], v);
  }
}

// ---------------- K3: nf (fp32 VALU) + Aq/Ak/vf via MFMA; block 1024 = t1 (R17b fold) ----------------
__global__ __launch_bounds__(256) void feat_kernel(
    const float* __restrict__ feat, const float* __restrict__ pre_w, const float* __restrict__ pre_b,
    const __hip_bfloat16* __restrict__ WQ2b, const __hip_bfloat16* __restrict__ WK2b,
    const __hip_bfloat16* __restrict__ WVb, const float* __restrict__ wv_b,
    float* __restrict__ nf, __hip_bfloat16* __restrict__ AqTb,
    __hip_bfloat16* __restrict__ AkTb, __hip_bfloat16* __restrict__ vfTb,
    const float* __restrict__ rst,
    const float* __restrict__ pos1_w, const float* __restrict__ pos1_b,
    const float* __restrict__ pos1_g, const float* __restrict__ pos1_be,
    float* __restrict__ s1, float* __restrict__ t1) {
  if (blockIdx.x == 1024) {
    // ---- t1 body (verbatim former t1_kernel; feat launches after knn so rst is ready) ----
    __shared__ float gsum[16], gsum2[16];
    int t = threadIdx.x;
    if (t < 16) { gsum[t] = 0.f; gsum2[t] = 0.f; }
    __syncthreads();
    int b = t >> 7, c = t & 127;
    const float* S = rst + b * 16;
    const float Minv = 1.0f / (float)(NN * KK);
    float mx = S[0] * Minv, my = S[1] * Minv, mz = S[2] * Minv;
    float Mxx = S[3] * Minv, Mxy = S[4] * Minv, Mxz = S[5] * Minv;
    float Myy = S[6] * Minv, Myz = S[7] * Minv, Mzz = S[8] * Minv;
    float w0 = pos1_w[c * 3], w1 = pos1_w[c * 3 + 1], w2 = pos1_w[c * 3 + 2];
    float bb = pos1_b[c];
    float wm = w0 * mx + w1 * my + w2 * mz;
    float Ey = wm + bb;
    float q = w0 * w0 * Mxx + w1 * w1 * Myy + w2 * w2 * Mzz
            + 2.f * (w0 * w1 * Mxy + w0 * w2 * Mxz + w1 * w2 * Myz);
    float Ey2 = q + 2.f * bb * wm + bb * bb;
    int g = c >> 4;
    atomicAdd(&gsum[b * 8 + g], Ey);
    atomicAdd(&gsum2[b * 8 + g], Ey2);
    __syncthreads();
    float mean = gsum[b * 8 + g] * (1.f / 16.f);
    float var = fmaxf(gsum2[b * 8 + g] * (1.f / 16.f) - mean * mean, 0.f);
    float r = rsqrtf(var + EPSV);
    float sv = pos1_g[c] * r;
    s1[t] = sv;
    t1[t] = fmaf(sv, bb, pos1_be[c] - mean * sv);
    return;
  }
  int b = blockIdx.x >> 9;
  int n0 = (blockIdx.x & 511) << 4;
  __shared__ float fe[64][20];
  __shared__ float nfs[128][20];
  __shared__ __align__(16) unsigned short zb[16][136];   // bf16 nfs^T [point][ch]
  int t = threadIdx.x;
  int lane = t & 63, wid = t >> 6;
  int l15 = lane & 15, quad = lane >> 4;
  for (int e = t; e < 1024; e += 256) {
    int ci = e >> 4, nn2 = e & 15;
    fe[ci][nn2] = feat[(b * 64 + ci) * NN + n0 + nn2];
  }
  __syncthreads();
  int nq = t & 3, cw = t >> 2;
  {
    float acc[2][4];
#pragma unroll
    for (int m = 0; m < 2; ++m) {
      float bv = pre_b[cw + 64 * m];
      acc[m][0] = bv; acc[m][1] = bv; acc[m][2] = bv; acc[m][3] = bv;
    }
    for (int i = 0; i < 64; ++i) {
      float4 x = *(const float4*)&fe[i][nq << 2];
      float w0 = pre_w[cw * 64 + i];
      float w1 = pre_w[(cw + 64) * 64 + i];
      acc[0][0] = fmaf(w0, x.x, acc[0][0]); acc[0][1] = fmaf(w0, x.y, acc[0][1]);
      acc[0][2] = fmaf(w0, x.z, acc[0][2]); acc[0][3] = fmaf(w0, x.w, acc[0][3]);
      acc[1][0] = fmaf(w1, x.x, acc[1][0]); acc[1][1] = fmaf(w1, x.y, acc[1][1]);
      acc[1][2] = fmaf(w1, x.z, acc[1][2]); acc[1][3] = fmaf(w1, x.w, acc[1][3]);
    }
#pragma unroll
    for (int m = 0; m < 2; ++m) {
      int c = cw + 64 * m;
      float4 v = make_float4(acc[m][0], acc[m][1], acc[m][2], acc[m][3]);
      *(float4*)&nfs[c][nq << 2] = v;
      *(float4*)&nf[(b * 128 + c) * NN + n0 + (nq << 2)] = v;
    }
  }
  __syncthreads();
  // ---- nfs (fp32 [ch][pt]) -> zb (bf16 [pt][ch]) ----
  {
    int cpp = t & 63, pg = t >> 6;
    int cp0 = cpp * 2;
#pragma unroll
    for (int i = 0; i < 4; ++i) {
      int pix = pg * 4 + i;
      *(unsigned*)&zb[pix][cp0] = pack2bf(nfs[cp0][pix], nfs[cp0 + 1][pix]);
    }
  }
  __syncthreads();
  // ---- 3 GEMMs on MFMA ----
  f32x4 acc[3][2];
#pragma unroll
  for (int g = 0; g < 3; ++g)
#pragma unroll
    for (int m2 = 0; m2 < 2; ++m2) acc[g][m2] = (f32x4){0.f, 0.f, 0.f, 0.f};
#pragma unroll
  for (int k0 = 0; k0 < 4; ++k0) {
    short8 bfr = *(const short8*)&zb[l15][k0 * 32 + quad * 8];
#pragma unroll
    for (int m2 = 0; m2 < 2; ++m2) {
      int off = ((wid * 2 + m2) * 16 + l15) * 128 + k0 * 32 + quad * 8;
      short8 aq = *(const short8*)((const unsigned short*)WQ2b + off);
      short8 ak = *(const short8*)((const unsigned short*)WK2b + off);
      short8 av = *(const short8*)((const unsigned short*)WVb + off);
      acc[0][m2] = __builtin_amdgcn_mfma_f32_16x16x32_bf16(aq, bfr, acc[0][m2], 0, 0, 0);
      acc[1][m2] = __builtin_amdgcn_mfma_f32_16x16x32_bf16(ak, bfr, acc[1][m2], 0, 0, 0);
      acc[2][m2] = __builtin_amdgcn_mfma_f32_16x16x32_bf16(av, bfr, acc[2][m2], 0, 0, 0);
    }
  }
  // ---- epilogue ----
  size_t pbase = ((size_t)(b * NN) + n0 + l15) * 128;
#pragma unroll
  for (int m2 = 0; m2 < 2; ++m2) {
    int crow = (wid * 2 + m2) * 16 + quad * 4;
    {
      f32x4 a = acc[0][m2];
      ushort4 o; o.x = f2bf(a[0]); o.y = f2bf(a[1]); o.z = f2bf(a[2]); o.w = f2bf(a[3]);
      *(ushort4*)((unsigned short*)AqTb + pbase + crow) = o;
    }
    {
      f32x4 a = acc[1][m2];
      ushort4 o; o.x = f2bf(a[0]); o.y = f2bf(a[1]); o.z = f2bf(a[2]); o.w = f2bf(a[3]);
      *(ushort4*)((unsigned short*)AkTb + pbase + crow) = o;
    }
    {
      f32x4 a = acc[2][m2];
      ushort4 o;
      o.x = f2bf(a[0] + wv_b[crow]);
      o.y = f2bf(a[1] + wv_b[crow + 1]);
      o.z = f2bf(a[2] + wv_b[crow + 2]);
      o.w = f2bf(a[3] + wv_b[crow + 3]);
      *(ushort4*)((unsigned short*)vfTb + pbase + crow) = o;
    }
  }
}

// ---------------- K5: y = W2@z + Aq - Ak + bias (MFMA), bf16 store + GN partials ----------------
__global__ __launch_bounds__(256) void y_kernel_mfma(const float* __restrict__ xyz,
    const int* __restrict__ idxb, const __hip_bfloat16* __restrict__ AqTb,
    const __hip_bfloat16* __restrict__ AkTb, const __hip_bfloat16* __restrict__ W2b,
    const float* __restrict__ bias_y, const float* __restrict__ pos1_w,
    const float* __restrict__ s1, const float* __restrict__ t1,
    __hip_bfloat16* __restrict__ ybuf, float* __restrict__ partA) {
  int b = blockIdx.x >> 11;
  int pb = (blockIdx.x & 2047) * 4;
  __shared__ __align__(16) __hip_bfloat16 z_s[64][136];
  __shared__ __align__(16) __hip_bfloat16 ak_s[64][136];
  __shared__ __align__(16) float aq_s[4][128];
  __shared__ float rel_s[64][4];
  __shared__ int jj[64];
  __shared__ float gns[8], gns2[8];
  int t = threadIdx.x;
  int lane = t & 63, wid = t >> 6;
  int l15 = lane & 15, quad = lane >> 4;
  if (t < 8) { gns[t] = 0.f; gns2[t] = 0.f; }
  if (t < 64) {
    int n = pb + (t >> 4);
    int j = idxb[(b * NN + pb) * 16 + t];
    jj[t] = j;
    const float* X = xyz + b * 3 * NN;
    rel_s[t][0] = X[j] - X[n];
    rel_s[t][1] = X[NN + j] - X[NN + n];
    rel_s[t][2] = X[2 * NN + j] - X[2 * NN + n];
  }
  for (int e = t; e < 512; e += 256) {
    int pt = e >> 7, c = e & 127;
    aq_s[pt][c] = bf2f(((const unsigned short*)AqTb)[((size_t)(b * NN) + pb + pt) * 128 + c]) + bias_y[c];
  }
  __syncthreads();
  {
    int cpp = t & 63, pg = t >> 6;
    int cp0 = cpp * 2;
    float w00 = pos1_w[cp0 * 3], w01 = pos1_w[cp0 * 3 + 1], w02 = pos1_w[cp0 * 3 + 2];
    float w10 = pos1_w[cp0 * 3 + 3], w11 = pos1_w[cp0 * 3 + 4], w12 = pos1_w[cp0 * 3 + 5];
    float sa = s1[b * 128 + cp0], ta = t1[b * 128 + cp0];
    float sb = s1[b * 128 + cp0 + 1], tb = t1[b * 128 + cp0 + 1];
#pragma unroll
    for (int i = 0; i < 16; ++i) {
      int pix = pg * 16 + i;
      float rx = rel_s[pix][0], ry = rel_s[pix][1], rz = rel_s[pix][2];
      float u0 = fmaf(w02, rz, fmaf(w01, ry, w00 * rx));
      float u1 = fmaf(w12, rz, fmaf(w11, ry, w10 * rx));
      float z0 = fmaf(sa, u0, ta); z0 = (z0 >= 0.f) ? z0 : 0.1f * z0;
      float z1 = fmaf(sb, u1, tb); z1 = (z1 >= 0.f) ? z1 : 0.1f * z1;
      *(unsigned*)&z_s[pix][cp0] = pack2bf(z0, z1);
    }
  }
  for (int e = t; e < 4096; e += 256) {
    int pix = e >> 6, cpp = e & 63;
    *(unsigned*)&ak_s[pix][cpp * 2] =
        *(const unsigned*)((const unsigned short*)AkTb + ((size_t)(b * NN) + jj[pix]) * 128 + cpp * 2);
  }
  short8 afr[2][4];
#pragma unroll
  for (int m2 = 0; m2 < 2; ++m2) {
    int row = (wid * 2 + m2) * 16 + l15;
#pragma unroll
    for (int k0 = 0; k0 < 4; ++k0)
      afr[m2][k0] = *(const short8*)((const unsigned short*)W2b + row * 128 + k0 * 32 + quad * 8);
  }
  __syncthreads();
  f32x4 acc[2][4];
#pragma unroll
  for (int m2 = 0; m2 < 2; ++m2)
#pragma unroll
    for (int nt = 0; nt < 4; ++nt) acc[m2][nt] = (f32x4){0.f, 0.f, 0.f, 0.f};
#pragma unroll
  for (int k0 = 0; k0 < 4; ++k0) {
#pragma unroll
    for (int nt = 0; nt < 4; ++nt) {
      short8 bfr = *(const short8*)&z_s[nt * 16 + l15][k0 * 32 + quad * 8];
      acc[0][nt] = __builtin_amdgcn_mfma_f32_16x16x32_bf16(afr[0][k0], bfr, acc[0][nt], 0, 0, 0);
      acc[1][nt] = __builtin_amdgcn_mfma_f32_16x16x32_bf16(afr[1][k0], bfr, acc[1][nt], 0, 0, 0);
    }
  }
  float lsum[2] = {0.f, 0.f}, lsum2[2] = {0.f, 0.f};
#pragma unroll
  for (int m2 = 0; m2 < 2; ++m2) {
    int c0 = (wid * 2 + m2) * 16 + quad * 4;
#pragma unroll
    for (int nt = 0; nt < 4; ++nt) {
      int pix = nt * 16 + l15;
      ushort4 au = *(ushort4*)&ak_s[pix][c0];
      float4 aq = *(float4*)&aq_s[nt][c0];
      f32x4 a = acc[m2][nt];
      float v0 = a[0] + aq.x - bf2f(au.x);
      float v1 = a[1] + aq.y - bf2f(au.y);
      float v2 = a[2] + aq.z - bf2f(au.z);
      float v3 = a[3] + aq.w - bf2f(au.w);
      lsum[m2] += (v0 + v1) + (v2 + v3);
      lsum2[m2] += fmaf(v0, v0, fmaf(v1, v1, fmaf(v2, v2, v3 * v3)));
      ushort4 yo;
      yo.x = f2bf(v0); yo.y = f2bf(v1); yo.z = f2bf(v2); yo.w = f2bf(v3);
      *(ushort4*)&ak_s[pix][c0] = yo;
    }
  }
#pragma unroll
  for (int m2 = 0; m2 < 2; ++m2) {
    float s = lsum[m2], s2 = lsum2[m2];
    for (int msk = 1; msk < 64; msk <<= 1) {
      s += __shfl_xor(s, msk);
      s2 += __shfl_xor(s2, msk);
    }
    if (lane == 0) {
      atomicAdd(&gns[wid * 2 + m2], s);
      atomicAdd(&gns2[wid * 2 + m2], s2);
    }
  }
  __syncthreads();
  size_t ybase = ((size_t)(b * NN) + pb) * 16;
  unsigned short* yb = (unsigned short*)ybuf;
  for (int e = t; e < 4096; e += 256) {
    int pix = e >> 6, cpp = e & 63;
    *(unsigned*)(yb + (ybase + pix) * 128 + cpp * 2) = *(unsigned*)&ak_s[pix][cpp * 2];
  }
  if (t < 8) {
    partA[(size_t)t * 4096 + blockIdx.x] = gns[t];
    partA[(size_t)(8 + t) * 4096 + blockIdx.x] = gns2[t];
  }
}

// ---------------- T3a: reduce GN partials [16][4096] -> red[32] ----------------
__global__ __launch_bounds__(256) void gnred_kernel(const float* __restrict__ part,
                                                    float* __restrict__ red) {
  int k = blockIdx.x;
  int pb = k >> 4, idx = k & 15;
  const float* p = part + (size_t)idx * 4096 + pb * 2048;
  float s = 0.f;
  for (int i = threadIdx.x; i < 2048; i += 256) s += p[i];
  __shared__ float rs[4];
  int lane = threadIdx.x & 63, wid = threadIdx.x >> 6;
  for (int off = 32; off; off >>= 1) s += __shfl_xor(s, off);
  if (lane == 0) rs[wid] = s;
  __syncthreads();
  if (threadIdx.x == 0) red[k] = rs[0] + rs[1] + rs[2] + rs[3];
}

// ---------------- K7: scores=A2@h (MFMA) + per-thread softmax (inline gnaff) ----------------
__global__ __launch_bounds__(256) void att_out_kernel(const __hip_bfloat16* __restrict__ ybuf,
    const int* __restrict__ idxb, const float* __restrict__ redA,
    const float* __restrict__ att1_g, const float* __restrict__ att1_be,
    const __hip_bfloat16* __restrict__ A2b, const __hip_bfloat16* __restrict__ vfTb,
    const float* __restrict__ nf, const float* __restrict__ PWT, const float* __restrict__ post_b,
    float* __restrict__ out2, float* __restrict__ partP) {
  int b = blockIdx.x >> 11;
  int pb = (blockIdx.x & 2047) * 4;
  __shared__ __align__(16) union HS {
    unsigned short h[64][136];
    float sc[2][128][17];
  } hs;
  __shared__ __align__(16) __hip_bfloat16 v_s[64][136];
  __shared__ __align__(16) float opre[4][132];
  __shared__ int jj[64];
  __shared__ float gns[8], gns2[8];
  int t = threadIdx.x;
  int lane = t & 63, wid = t >> 6;
  int l15 = lane & 15, quad = lane >> 4;
  if (t < 8) { gns[t] = 0.f; gns2[t] = 0.f; }
  if (t < 64) jj[t] = idxb[(b * NN + pb) * 16 + t];
  __syncthreads();
  size_t ybase = ((size_t)(b * NN) + pb) * 16;
  const unsigned short* yb = (const unsigned short*)ybuf;
  {
    int cpp = t & 63, pg = t >> 6;
    int c0 = cpp * 2;
    const float Minv = 1.0f / 2097152.0f;
    int g = c0 >> 4;
    float S = redA[b * 16 + g], S2v = redA[b * 16 + 8 + g];
    float mean = S * Minv;
    float var = fmaxf(S2v * Minv - mean * mean, 0.f);
    float r = rsqrtf(var + EPSV);
    float sa = att1_g[c0] * r;
    float ta = att1_be[c0] - mean * sa;
    float sb = att1_g[c0 + 1] * r;
    float tb = att1_be[c0 + 1] - mean * sb;
#pragma unroll
    for (int i = 0; i < 16; ++i) {
      int pix = pg * 16 + i;
      unsigned u = *(const unsigned*)(yb + (ybase + pix) * 128 + c0);
      float y0 = bf2f((unsigned short)(u & 0xffff));
      float y1 = bf2f((unsigned short)(u >> 16));
      float h0 = fmaf(sa, y0, ta); h0 = (h0 >= 0.f) ? h0 : 0.1f * h0;
      float h1 = fmaf(sb, y1, tb); h1 = (h1 >= 0.f) ? h1 : 0.1f * h1;
      *(unsigned*)&hs.h[pix][c0] = pack2bf(h0, h1);
    }
  }
  for (int e = t; e < 4096; e += 256) {
    int pix = e >> 6, cpp = e & 63;
    *(unsigned*)&v_s[pix][cpp * 2] =
        *(const unsigned*)((const unsigned short*)vfTb + ((size_t)(b * NN) + jj[pix]) * 128 + cpp * 2);
  }
  short8 afr[2][4];
#pragma unroll
  for (int m2 = 0; m2 < 2; ++m2) {
    int row = (wid * 2 + m2) * 16 + l15;
#pragma unroll
    for (int k0 = 0; k0 < 4; ++k0)
      afr[m2][k0] = *(const short8*)((const unsigned short*)A2b + row * 128 + k0 * 32 + quad * 8);
  }
  __syncthreads();
  f32x4 acc[2][4];
#pragma unroll
  for (int m2 = 0; m2 < 2; ++m2)
#pragma unroll
    for (int nt = 0; nt < 4; ++nt) acc[m2][nt] = (f32x4){0.f, 0.f, 0.f, 0.f};
#pragma unroll
  for (int k0 = 0; k0 < 4; ++k0) {
#pragma unroll
    for (int nt = 0; nt < 4; ++nt) {
      short8 bfr = *(const short8*)&hs.h[nt * 16 + l15][k0 * 32 + quad * 8];
      acc[0][nt] = __builtin_amdgcn_mfma_f32_16x16x32_bf16(afr[0][k0], bfr, acc[0][nt], 0, 0, 0);
      acc[1][nt] = __builtin_amdgcn_mfma_f32_16x16x32_bf16(afr[1][k0], bfr, acc[1][nt], 0, 0, 0);
    }
  }
  int pidx = t >> 7;
  int cch = t & 127;
#pragma unroll
  for (int pass = 0; pass < 2; ++pass) {
    __syncthreads();
#pragma unroll
    for (int ntl = 0; ntl < 2; ++ntl) {
      int nt = pass * 2 + ntl;
#pragma unroll
      for (int m2 = 0; m2 < 2; ++m2) {
        int cb = (wid * 2 + m2) * 16 + quad * 4;
        f32x4 a = acc[m2][nt];
#pragma unroll
        for (int r = 0; r < 4; ++r) hs.sc[ntl][cb + r][l15] = a[r];
      }
    }
    __syncthreads();
    {
      int p = pass * 2 + pidx;
      float nfv = nf[(size_t)(b * 128 + cch) * NN + pb + p];
      const float* srow = hs.sc[pidx][cch];
      float sv[16];
#pragma unroll
      for (int k = 0; k < 16; ++k) sv[k] = srow[k];
      float mx = sv[0];
#pragma unroll
      for (int k = 1; k < 16; ++k) mx = fmaxf(mx, sv[k]);
      float sm = 0.f, dot = 0.f;
#pragma unroll
      for (int k = 0; k < 16; ++k) {
        float e = __expf(sv[k] - mx);
        sm += e;
        float vv = bf2f(*(const unsigned short*)&v_s[p * 16 + k][cch]);
        dot = fmaf(e, vv, dot);
      }
      opre[p][cch] = dot / sm + nfv;
    }
  }
  __syncthreads();
  {
    int c = t & 127, g = t >> 7;
    float a0 = post_b[c], a1 = a0;
    for (int cp = 0; cp < 128; ++cp) {
      float w = PWT[cp * 128 + c];
      a0 = fmaf(w, opre[g * 2][cp], a0);
      a1 = fmaf(w, opre[g * 2 + 1][cp], a1);
    }
    out2[(size_t)(b * 128 + c) * NN + pb + g * 2] = a0;
    out2[(size_t)(b * 128 + c) * NN + pb + g * 2 + 1] = a1;
    atomicAdd(&gns[c >> 4], a0 + a1);
    atomicAdd(&gns2[c >> 4], fmaf(a0, a0, a1 * a1));
  }
  __syncthreads();
  if (t < 8) {
    partP[(size_t)t * 4096 + blockIdx.x] = gns[t];
    partP[(size_t)(8 + t) * 4096 + blockIdx.x] = gns2[t];
  }
}

// ---------------- K9: final normalize + lrelu (gnaff inline, float4) ----------------
__global__ __launch_bounds__(256) void final_kernel(const float* __restrict__ out2,
    const float* __restrict__ redP, const float* __restrict__ post_g,
    const float* __restrict__ post_be, float* __restrict__ out) {
  int e4 = blockIdx.x * 256 + threadIdx.x;   // 0..524287
  int base = e4 * 4;
  int c = (base >> 13) & 127, b = base >> 20;
  const float Minv = 1.0f / 131072.0f;
  int g = c >> 4;
  float S = redP[b * 16 + g], S2 = redP[b * 16 + 8 + g];
  float mean = S * Minv;
  float var = fmaxf(S2 * Minv - mean * mean, 0.f);
  float r = rsqrtf(var + EPSV);
  float sv = post_g[c] * r;
  float tv = post_be[c] - mean * sv;
  float4 x = *(const float4*)&out2[base];
  float4 o;
  o.x = fmaf(sv, x.x, tv); o.x = (o.x >= 0.f) ? o.x : 0.1f * o.x;
  o.y = fmaf(sv, x.y, tv); o.y = (o.y >= 0.f) ? o.y : 0.1f * o.y;
  o.z = fmaf(sv, x.z, tv); o.z = (o.z >= 0.f) ? o.z : 0.1f * o.z;
  o.w = fmaf(sv, x.w, tv); o.w = (o.w >= 0.f) ? o.w : 0.1f * o.w;
  *(float4*)&((float*)out)[base] = o;
}

// ---------------- launch ----------------
extern "C" void kernel_launch(void* const* d_in, const int* in_sizes, int n_in,
                              void* d_out, int out_size, void* d_ws, size_t ws_size,
                              hipStream_t stream) {
  (void)in_sizes; (void)n_in; (void)out_size; (void)ws_size;
  const float* xyz     = (const float*)d_in[0];
  const float* feat    = (const float*)d_in[1];
  const float* pre_w   = (const float*)d_in[2];
  const float* pre_b   = (const float*)d_in[3];
  const float* wq_w    = (const float*)d_in[4];
  const float* wq_b    = (const float*)d_in[5];
  const float* wk_w    = (const float*)d_in[6];
  const float* wk_b    = (const float*)d_in[7];
  const float* wv_w    = (const float*)d_in[8];
  const float* wv_b    = (const float*)d_in[9];
  const float* pos1_w  = (const float*)d_in[10];
  const float* pos1_b  = (const float*)d_in[11];
  const float* pos1_g  = (const float*)d_in[12];
  const float* pos1_be = (const float*)d_in[13];
  const float* pos2_w  = (const float*)d_in[14];
  const float* pos2_b  = (const float*)d_in[15];
  const float* att1_w  = (const float*)d_in[16];
  const float* att1_b  = (const float*)d_in[17];
  const float* att1_g  = (const float*)d_in[18];
  const float* att1_be = (const float*)d_in[19];
  const float* att2_w  = (const float*)d_in[20];
  // d_in[21] = att2_b: constant over k -> cancels in softmax
  const float* post_w  = (const float*)d_in[22];
  const float* post_b  = (const float*)d_in[23];
  const float* post_g  = (const float*)d_in[24];
  const float* post_be = (const float*)d_in[25];

  float* W = (float*)d_ws;
  int* idxb = (int*)d_ws;
  float* nf   = W + OFF_NF;
  float* out2 = W + OFF_OUT2;
  __hip_bfloat16* ybuf = (__hip_bfloat16*)(W + OFF_Y);
  __hip_bfloat16* AqTb = (__hip_bfloat16*)(W + OFF_AQB);
  __hip_bfloat16* AkTb = (__hip_bfloat16*)(W + OFF_AKB);
  __hip_bfloat16* vfTb = (__hip_bfloat16*)(W + OFF_VFB);
  __hip_bfloat16* WQ2B = (__hip_bfloat16*)(W + OFF_WQ2);          // bf16 128x128
  __hip_bfloat16* WVB  = (__hip_bfloat16*)(W + OFF_WQ2 + 8192);   // bf16 128x128
  __hip_bfloat16* WK2B = (__hip_bfloat16*)(W + OFF_WK2);          // bf16 128x128
  float* PWT  = W + OFF_PWT;
  __hip_bfloat16* W2b = (__hip_bfloat16*)(W + OFF_W2B);
  __hip_bfloat16* A2b = (__hip_bfloat16*)(W + OFF_A2B);
  float* BY   = W + OFF_BY;
  float* RST  = W + OFF_RST;
  float* REDA = W + OFF_REDA;
  float* REDP = W + OFF_REDP;
  float* S1 = W + OFF_S1; float* T1 = W + OFF_T1;
  float4* PTS4 = (float4*)(W + OFF_PTS4);
  float* PARTA = W + OFF_PTA;
  float* PARTP = W + OFF_PTP;

  hipMemsetAsync(RST, 0, 32 * sizeof(float), stream);

  prep_weights<<<258, 128, 0, stream>>>(att1_w, wq_w, wk_w, pos2_w, att2_w, post_w, wv_w,
                                        wq_b, wk_b, pos2_b, att1_b, xyz,
                                        WQ2B, WK2B, WVB, W2b, A2b, PWT, BY, PTS4);
  knn_kernel<<<1024, 256, 0, stream>>>(PTS4, idxb, RST);
  feat_kernel<<<1025, 256, 0, stream>>>(feat, pre_w, pre_b, WQ2B, WK2B, WVB, wv_b,
                                        nf, AqTb, AkTb, vfTb,
                                        RST, pos1_w, pos1_b, pos1_g, pos1_be, S1, T1);
  y_kernel_mfma<<<4096, 256, 0, stream>>>(xyz, idxb, AqTb, AkTb, W2b, BY, pos1_w, S1, T1, ybuf, PARTA);
  gnred_kernel<<<32, 256, 0, stream>>>(PARTA, REDA);
  att_out_kernel<<<4096, 256, 0, stream>>>(ybuf, idxb, REDA, att1_g, att1_be,
                                           A2b, vfTb, nf, PWT, post_b, out2, PARTP);
  gnred_kernel<<<32, 256, 0, stream>>>(PARTP, REDP);
  final_kernel<<<2048, 256, 0, stream>>>(out2, REDP, post_g, post_be, (float*)d_out);
}